// Round 7
// baseline (1593.126 us; speedup 1.0000x reference)
//
#include <hip/hip_runtime.h>
#include <math.h>

#define NNODES 100000
#define NEDGES 1600000
#define NGROUP (NEDGES / 4)    // 4-edge groups (setup / f2)
#define NGROUP2 (NEDGES / 2)   // 2-edge groups (layer kernels)
#define NLAYERS 20
#define NB 256          // accumulator banks == BLK; blocks/bank ~12 -> short RMW chains
#define BLK 256
#define GRIDE 1024                          // stride kernels (setup)
#define STRIDE (GRIDE * BLK)
#define GRID2 ((NGROUP2 + BLK - 1) / BLK)   // 3125: one 2-edge group per thread
#define GRIDL ((NGROUP + BLK - 1) / BLK)    // 1563: one 4-edge group per thread
#define NBLKN ((NNODES + 255) / 256)        // 391 blocks for node kernels

// ---- block reduce of N float stats -> N parallel f64 atomics (one per lane) ----
template<int N>
__device__ __forceinline__ void block_stats_atomic(const float* vals, double* base) {
  __shared__ double sm[16][4];
  int lane = threadIdx.x & 63, wid = threadIdx.x >> 6;
  __syncthreads();                  // guard back-to-back calls reusing sm
  #pragma unroll
  for (int n = 0; n < N; ++n) {
    double d = (double)vals[n];
    #pragma unroll
    for (int o = 32; o > 0; o >>= 1) d += __shfl_down(d, o, 64);
    if (lane == 0) sm[n][wid] = d;
  }
  __syncthreads();
  if (threadIdx.x < N) {
    double s = sm[threadIdx.x][0] + sm[threadIdx.x][1] + sm[threadIdx.x][2] + sm[threadIdx.x][3];
    atomicAdd(base + threadIdx.x, s);   // N atomics issue in parallel from N lanes
  }
}

// ---- cooperative reduction over NB banks: res[s] = sum_bk acc[bk*8+s] ----
// BLK==NB: thread t owns bank t. Must be called by ALL threads (before any return).
template<int NS>
__device__ __forceinline__ void bank_reduce(const double* __restrict__ acc, double* res) {
  __shared__ double red[BLK * 8];   // 16 KB
  int t = threadIdx.x;
  #pragma unroll
  for (int s = 0; s < NS; ++s) red[t * 8 + s] = acc[t * 8 + s];
  __syncthreads();
  for (int o = BLK / 2; o > 0; o >>= 1) {
    if (t < o) {
      #pragma unroll
      for (int s = 0; s < NS; ++s) red[t * 8 + s] += red[(t + o) * 8 + s];
    }
    __syncthreads();
  }
  #pragma unroll
  for (int s = 0; s < NS; ++s) res[s] = red[s];   // same-address broadcast
  __syncthreads();
}

// x = [mi, mj, h] @ W1 + b1  (9->4)
__device__ __forceinline__ void compute_x(const float4 mi, const float4 mj,
    float h0, float h1, float h2,
    const float* __restrict__ w, const float* __restrict__ b, float* x) {
  #pragma unroll
  for (int j = 0; j < 4; ++j) {
    float t = b[j];
    t += mi.x * w[0 * 4 + j]; t += mi.y * w[1 * 4 + j]; t += mi.z * w[2 * 4 + j];
    t += mj.x * w[3 * 4 + j]; t += mj.y * w[4 * 4 + j]; t += mj.z * w[5 * 4 + j];
    t += h0 * w[6 * 4 + j];  t += h1 * w[7 * 4 + j];  t += h2 * w[8 * 4 + j];
    x[j] = t;
  }
}

// ---------------- kz: pad-copy M, zero hist + accums ----------------
__global__ void __launch_bounds__(BLK) kz(const float* __restrict__ Min,
                                          float* __restrict__ M,
                                          int* __restrict__ hist,
                                          double* __restrict__ accs) {
  int tid = blockIdx.x * BLK + threadIdx.x;
  for (int v = tid; v < NNODES; v += STRIDE) {
    float4 m;
    m.x = Min[3 * v]; m.y = Min[3 * v + 1]; m.z = Min[3 * v + 2]; m.w = 0.f;
    *(float4*)(M + 4 * (size_t)v) = m;
    hist[v] = 0;
  }
  for (int i = tid; i < 3 * NB * 8; i += STRIDE) accs[i] = 0.0;
}

// ---------------- khr: histogram of dst, save rank (atomic return) ----------
__global__ void __launch_bounds__(BLK) khr(const int* __restrict__ dst,
                                           int* __restrict__ hist,
                                           int* __restrict__ rankpos) {
  int g = blockIdx.x * BLK + threadIdx.x;
  if (g >= NGROUP) return;
  int4 d4 = ((const int4*)dst)[g];
  int4 r;
  r.x = atomicAdd(&hist[d4.x], 1);
  r.y = atomicAdd(&hist[d4.y], 1);
  r.z = atomicAdd(&hist[d4.z], 1);
  r.w = atomicAdd(&hist[d4.w], 1);
  ((int4*)rankpos)[g] = r;
}

// ---------------- ksA: per-block sums of hist ----------------
__global__ void __launch_bounds__(256) ksA(const int* __restrict__ hist,
                                           int* __restrict__ bsum) {
  __shared__ int sm[256];
  int i = blockIdx.x * 256 + threadIdx.x;
  sm[threadIdx.x] = (i < NNODES) ? hist[i] : 0;
  __syncthreads();
  for (int o = 128; o > 0; o >>= 1) {
    if (threadIdx.x < o) sm[threadIdx.x] += sm[threadIdx.x + o];
    __syncthreads();
  }
  if (threadIdx.x == 0) bsum[blockIdx.x] = sm[0];
}

// ---------------- ksB: exclusive scan of the 391 block sums (1 block) -------
__global__ void __launch_bounds__(512) ksB(const int* __restrict__ bsum,
                                           int* __restrict__ bbase) {
  __shared__ int sm[512];
  int t = threadIdx.x;
  sm[t] = (t < NBLKN) ? bsum[t] : 0;
  __syncthreads();
  for (int o = 1; o < 512; o <<= 1) {
    int v = (t >= o) ? sm[t - o] : 0;
    __syncthreads();
    sm[t] += v;
    __syncthreads();
  }
  if (t < NBLKN) bbase[t] = (t == 0) ? 0 : sm[t - 1];
}

// ---------------- ksC: per-element offsets ----------------
__global__ void __launch_bounds__(256) ksC(const int* __restrict__ hist,
                                           const int* __restrict__ bbase,
                                           int* __restrict__ off) {
  __shared__ int sm[256];
  int t = threadIdx.x;
  int i = blockIdx.x * 256 + t;
  int v = (i < NNODES) ? hist[i] : 0;
  sm[t] = v;
  __syncthreads();
  for (int o = 1; o < 256; o <<= 1) {
    int u = (t >= o) ? sm[t - o] : 0;
    __syncthreads();
    sm[t] += u;
    __syncthreads();
  }
  if (i < NNODES) off[i] = bbase[blockIdx.x] + sm[t] - v;
  if (i == 0) off[NNODES] = NEDGES;
}

// ---------------- kp1: pos[e] = off[dst]+rank (in-place), eperm scatter -----
__global__ void __launch_bounds__(BLK) kp1(const int* __restrict__ dst,
                                           const int* __restrict__ off,
                                           int* __restrict__ rankpos,
                                           int* __restrict__ eperm) {
  int g = blockIdx.x * BLK + threadIdx.x;
  if (g >= NGROUP) return;
  int4 d4 = ((const int4*)dst)[g];
  int4 r4 = ((int4*)rankpos)[g];
  int4 p4;
  p4.x = off[d4.x] + r4.x;
  p4.y = off[d4.y] + r4.y;
  p4.z = off[d4.z] + r4.z;
  p4.w = off[d4.w] + r4.w;
  int e = 4 * g;
  eperm[p4.x] = e; eperm[p4.y] = e + 1; eperm[p4.z] = e + 2; eperm[p4.w] = e + 3;
  ((int4*)rankpos)[g] = p4;   // rankpos now holds pos[e]
}

// ---------------- kp2: gather into CSR order, streaming writes --------------
__global__ void __launch_bounds__(BLK) kp2(const int* __restrict__ src,
                                           const int* __restrict__ dst,
                                           const float* __restrict__ Hin,
                                           const int* __restrict__ eperm,
                                           int* __restrict__ sp,
                                           int* __restrict__ dp,
                                           float* __restrict__ Hp) {
  int g = blockIdx.x * BLK + threadIdx.x;
  if (g >= NGROUP) return;
  int4 e4 = ((const int4*)eperm)[g];
  int4 s4, d4;
  s4.x = src[e4.x]; d4.x = dst[e4.x];
  s4.y = src[e4.y]; d4.y = dst[e4.y];
  s4.z = src[e4.z]; d4.z = dst[e4.z];
  s4.w = src[e4.w]; d4.w = dst[e4.w];
  float h[4][3];
  int ee[4] = {e4.x, e4.y, e4.z, e4.w};
  #pragma unroll
  for (int k = 0; k < 4; ++k) {
    size_t e3 = 3 * (size_t)ee[k];
    h[k][0] = Hin[e3]; h[k][1] = Hin[e3 + 1]; h[k][2] = Hin[e3 + 2];
  }
  ((int4*)sp)[g] = s4;
  ((int4*)dp)[g] = d4;
  float4 hA, hB, hC;
  hA.x = h[0][0]; hA.y = h[0][1]; hA.z = h[0][2]; hA.w = h[1][0];
  hB.x = h[1][1]; hB.y = h[1][2]; hB.z = h[2][0]; hB.w = h[2][1];
  hC.x = h[2][2]; hC.y = h[3][0]; hC.z = h[3][1]; hC.w = h[3][2];
  float4* Hv = (float4*)Hp + 3 * (size_t)g;
  Hv[0] = hA; Hv[1] = hB; Hv[2] = hC;
}

// ---------------- K1: stats of x = e_in @ W1 + b1 ; zero acc2 ----------------
__global__ void __launch_bounds__(BLK) k1(
    const float* __restrict__ M, const float* __restrict__ H,
    const int* __restrict__ sp, const int* __restrict__ dp,
    const float* __restrict__ W1, const float* __restrict__ b1,
    double* __restrict__ acc1, double* __restrict__ acc2) {
  int g = blockIdx.x * BLK + threadIdx.x;
  if (blockIdx.x == 0)
    for (int i = threadIdx.x; i < NB * 8; i += BLK) acc2[i] = 0.0;

  float sx[4] = {0, 0, 0, 0}, sq[4] = {0, 0, 0, 0};
  if (g < NGROUP2) {
    int2 s2 = ((const int2*)sp)[g];
    int2 d2 = ((const int2*)dp)[g];
    const float2* Hv = (const float2*)H + 3 * (size_t)g;
    float2 h0 = Hv[0], h1 = Hv[1], h2 = Hv[2];
    float4 miA = *(const float4*)(M + 4 * (size_t)d2.x);
    float4 mjA = *(const float4*)(M + 4 * (size_t)s2.x);
    float4 miB = *(const float4*)(M + 4 * (size_t)d2.y);
    float4 mjB = *(const float4*)(M + 4 * (size_t)s2.y);
    float x[2][4];
    compute_x(miA, mjA, h0.x, h0.y, h1.x, W1, b1, x[0]);
    compute_x(miB, mjB, h1.y, h2.x, h2.y, W1, b1, x[1]);
    #pragma unroll
    for (int k = 0; k < 2; ++k)
      #pragma unroll
      for (int j = 0; j < 4; ++j) { sx[j] += x[k][j]; sq[j] += x[k][j] * x[k][j]; }
  }
  float vals[8] = {sx[0], sx[1], sx[2], sx[3], sq[0], sq[1], sq[2], sq[3]};
  block_stats_atomic<8>(vals, acc1 + (size_t)(blockIdx.x & (NB - 1)) * 8);
}

// ---------------- K2: Hn per edge + stats of z ; (layer19) head-BN stats ----
__global__ void __launch_bounds__(BLK) k2(
    const float* __restrict__ M, const float* __restrict__ H, float* __restrict__ Hn,
    const int* __restrict__ sp, const int* __restrict__ dp,
    const float* __restrict__ W1, const float* __restrict__ b1,
    const float* __restrict__ g1, const float* __restrict__ be1,
    const float* __restrict__ W2, const float* __restrict__ b2,
    const float* __restrict__ V1, const float* __restrict__ vb1,
    const double* __restrict__ acc1, double* __restrict__ acc2,
    int isFinal,
    const float* __restrict__ OW1, const float* __restrict__ ob1,
    double* __restrict__ accF) {
  double red[8];
  bank_reduce<8>(acc1, red);
  float s1[4], t1[4];
  {
    const double invE = 1.0 / (double)NEDGES;
    #pragma unroll
    for (int j = 0; j < 4; ++j) {
      double m = red[j] * invE;
      double var = red[4 + j] * invE - m * m;
      double sc = (double)g1[j] / sqrt(var + 1e-5);
      s1[j] = (float)sc;
      t1[j] = (float)((double)be1[j] - m * sc);
    }
  }
  float sz[3] = {0, 0, 0}, szz[3] = {0, 0, 0}, sf[3] = {0, 0, 0}, sff[3] = {0, 0, 0};
  int g = blockIdx.x * BLK + threadIdx.x;
  if (g < NGROUP2) {
    int2 s2v = ((const int2*)sp)[g];
    int2 d2v = ((const int2*)dp)[g];
    const float2* Hv = (const float2*)H + 3 * (size_t)g;
    float2 ha = Hv[0], hb = Hv[1], hc = Hv[2];
    float4 mi[2], mj[2];
    mi[0] = *(const float4*)(M + 4 * (size_t)d2v.x);
    mj[0] = *(const float4*)(M + 4 * (size_t)s2v.x);
    mi[1] = *(const float4*)(M + 4 * (size_t)d2v.y);
    mj[1] = *(const float4*)(M + 4 * (size_t)s2v.y);
    float h[2][3] = {{ha.x, ha.y, hb.x}, {hb.y, hc.x, hc.y}};
    float hn[2][3];
    #pragma unroll
    for (int k = 0; k < 2; ++k) {
      float x[4], y[4];
      compute_x(mi[k], mj[k], h[k][0], h[k][1], h[k][2], W1, b1, x);
      #pragma unroll
      for (int j = 0; j < 4; ++j) y[j] = fmaxf(x[j] * s1[j] + t1[j], 0.f);
      #pragma unroll
      for (int c = 0; c < 3; ++c) {
        hn[k][c] = b2[c] + y[0] * W2[0 * 3 + c] + y[1] * W2[1 * 3 + c]
                         + y[2] * W2[2 * 3 + c] + y[3] * W2[3 * 3 + c];
      }
      #pragma unroll
      for (int c = 0; c < 3; ++c) {
        float z = vb1[c] + mi[k].x * V1[0 * 3 + c] + mi[k].y * V1[1 * 3 + c] + mi[k].z * V1[2 * 3 + c]
                         + hn[k][0] * V1[3 * 3 + c] + hn[k][1] * V1[4 * 3 + c] + hn[k][2] * V1[5 * 3 + c];
        sz[c] += z; szz[c] += z * z;
      }
      if (isFinal) {
        #pragma unroll
        for (int c = 0; c < 3; ++c) {
          float f = ob1[c] + hn[k][0] * OW1[0 * 3 + c] + hn[k][1] * OW1[1 * 3 + c] + hn[k][2] * OW1[2 * 3 + c];
          sf[c] += f; sff[c] += f * f;
        }
      }
    }
    float2* Hw = (float2*)Hn + 3 * (size_t)g;
    float2 oA, oB, oC;
    oA.x = hn[0][0]; oA.y = hn[0][1];
    oB.x = hn[0][2]; oB.y = hn[1][0];
    oC.x = hn[1][1]; oC.y = hn[1][2];
    Hw[0] = oA; Hw[1] = oB; Hw[2] = oC;
  }
  size_t bank = (size_t)(blockIdx.x & (NB - 1)) * 8;
  float v6[6] = {sz[0], sz[1], sz[2], szz[0], szz[1], szz[2]};
  block_stats_atomic<6>(v6, acc2 + bank);
  if (isFinal) {
    float v6b[6] = {sf[0], sf[1], sf[2], sff[0], sff[1], sff[2]};
    block_stats_atomic<6>(v6b, accF + bank);
  }
}

// ---------------- K3: node-centric aggregation via CSR; zero acc1 ----------
__global__ void __launch_bounds__(BLK) k3(
    const float* __restrict__ M, const float* __restrict__ Hn,
    const int* __restrict__ off,
    const float* __restrict__ V1, const float* __restrict__ vb1,
    const float* __restrict__ vg1, const float* __restrict__ vbe1,
    const float* __restrict__ V2, const float* __restrict__ vb2,
    const double* __restrict__ acc2, double* __restrict__ acc1,
    float* __restrict__ Mnew) {
  double red[6];
  bank_reduce<6>(acc2, red);
  float s2[3], t2[3];
  {
    const double invE = 1.0 / (double)NEDGES;
    #pragma unroll
    for (int c = 0; c < 3; ++c) {
      double m = red[c] * invE;
      double var = red[3 + c] * invE - m * m;
      double sc = (double)vg1[c] / sqrt(var + 1e-5);
      s2[c] = (float)sc;
      t2[c] = (float)((double)vbe1[c] - m * sc);
    }
  }
  if (blockIdx.x == 0)
    for (int i = threadIdx.x; i < NB * 8; i += BLK) acc1[i] = 0.0;

  int v = blockIdx.x * BLK + threadIdx.x;
  if (v >= NNODES) return;
  float4 mi = *(const float4*)(M + 4 * (size_t)v);
  int e0 = off[v], e1 = off[v + 1];
  float a0 = 0.f, a1 = 0.f, a2v = 0.f;
  for (int e = e0; e < e1; ++e) {
    size_t e3 = 3 * (size_t)e;
    float h0 = Hn[e3], h1 = Hn[e3 + 1], h2 = Hn[e3 + 2];
    float y[3];
    #pragma unroll
    for (int c = 0; c < 3; ++c) {
      float z = vb1[c] + mi.x * V1[0 * 3 + c] + mi.y * V1[1 * 3 + c] + mi.z * V1[2 * 3 + c]
                       + h0 * V1[3 * 3 + c] + h1 * V1[4 * 3 + c] + h2 * V1[5 * 3 + c];
      y[c] = fmaxf(z * s2[c] + t2[c], 0.f);
    }
    a0  += vb2[0] + y[0] * V2[0] + y[1] * V2[3] + y[2] * V2[6];
    a1  += vb2[1] + y[0] * V2[1] + y[1] * V2[4] + y[2] * V2[7];
    a2v += vb2[2] + y[0] * V2[2] + y[1] * V2[5] + y[2] * V2[8];
  }
  float4 o; o.x = a0; o.y = a1; o.z = a2v; o.w = 0.f;
  *(float4*)(Mnew + 4 * (size_t)v) = o;
}

// ---------------- head: gather H via pos, streamed out writes ----------------
__global__ void __launch_bounds__(BLK) f2(
    const float* __restrict__ H, const int* __restrict__ pos,
    const float* __restrict__ OW1, const float* __restrict__ ob1,
    const float* __restrict__ og, const float* __restrict__ obe,
    const float* __restrict__ OW2, const float* __restrict__ ob2,
    const double* __restrict__ accF, float* __restrict__ out) {
  double red[6];
  bank_reduce<6>(accF, red);
  float sF[3], tF[3];
  {
    const double invE = 1.0 / (double)NEDGES;
    #pragma unroll
    for (int c = 0; c < 3; ++c) {
      double m = red[c] * invE;
      double var = red[3 + c] * invE - m * m;
      double sc = (double)og[c] / sqrt(var + 1e-5);
      sF[c] = (float)sc;
      tF[c] = (float)((double)obe[c] - m * sc);
    }
  }
  int g = blockIdx.x * BLK + threadIdx.x;
  if (g >= NGROUP) return;
  int4 p4 = ((const int4*)pos)[g];
  int p[4] = {p4.x, p4.y, p4.z, p4.w};
  float2 o[4];
  #pragma unroll
  for (int k = 0; k < 4; ++k) {
    size_t p3 = 3 * (size_t)p[k];
    float h0 = H[p3], h1 = H[p3 + 1], h2 = H[p3 + 2];
    float y[3];
    #pragma unroll
    for (int c = 0; c < 3; ++c) {
      float f = ob1[c] + h0 * OW1[0 * 3 + c] + h1 * OW1[1 * 3 + c] + h2 * OW1[2 * 3 + c];
      y[c] = fmaxf(f * sF[c] + tF[c], 0.f);
    }
    float l0 = ob2[0] + y[0] * OW2[0] + y[1] * OW2[2] + y[2] * OW2[4];
    float l1 = ob2[1] + y[0] * OW2[1] + y[1] * OW2[3] + y[2] * OW2[5];
    float mx = fmaxf(l0, l1);
    float e0 = __expf(l0 - mx), e1 = __expf(l1 - mx);
    float inv = 1.f / (e0 + e1);
    o[k].x = e0 * inv; o[k].y = e1 * inv;
  }
  float4 oA, oB;
  oA.x = o[0].x; oA.y = o[0].y; oA.z = o[1].x; oA.w = o[1].y;
  oB.x = o[2].x; oB.y = o[2].y; oB.z = o[3].x; oB.w = o[3].y;
  ((float4*)out)[2 * (size_t)g] = oA;
  ((float4*)out)[2 * (size_t)g + 1] = oB;
}

extern "C" void kernel_launch(void* const* d_in, const int* in_sizes, int n_in,
                              void* d_out, int out_size, void* d_ws, size_t ws_size,
                              hipStream_t stream) {
  const float* M_in   = (const float*)d_in[0];
  const float* H_in   = (const float*)d_in[1];
  const int*   ei     = (const int*)d_in[2];
  const float* we_w1  = (const float*)d_in[3];
  const float* we_b1  = (const float*)d_in[4];
  const float* we_g1  = (const float*)d_in[5];
  const float* we_be1 = (const float*)d_in[6];
  const float* we_w2  = (const float*)d_in[7];
  const float* we_b2  = (const float*)d_in[8];
  const float* wv_w1  = (const float*)d_in[9];
  const float* wv_b1  = (const float*)d_in[10];
  const float* wv_g1  = (const float*)d_in[11];
  const float* wv_be1 = (const float*)d_in[12];
  const float* wv_w2  = (const float*)d_in[13];
  const float* wv_b2  = (const float*)d_in[14];
  const float* out_w1 = (const float*)d_in[15];
  const float* out_b1 = (const float*)d_in[16];
  const float* out_g  = (const float*)d_in[17];
  const float* out_be = (const float*)d_in[18];
  const float* out_w2 = (const float*)d_in[19];
  const float* out_b2 = (const float*)d_in[20];
  const int* src = ei;
  const int* dst = ei + NEDGES;

  float* ws = (float*)d_ws;
  float* MA  = ws;                         // N*4
  float* MB  = ws + 400000;                // N*4
  float* Hp0 = ws + 800000;                // E*3 (16B-aligned)
  float* Hp1 = ws + 5600000;               // E*3
  int* eperm  = (int*)Hp1;                 // alias: dead before layer-0 k2 writes Hp1
  int* ib      = (int*)(ws + 10400000);    // 16B-aligned
  int* sp      = ib;                       // E
  int* dp      = ib + 1600000;             // E
  int* rankpos = ib + 3200000;             // E (rank, then pos)
  int* hist    = ib + 4800000;             // N
  int* off     = ib + 4900000;             // N+1
  int* bsum    = ib + 5000001;             // 400
  int* bbase   = ib + 5000401;             // 400
  double* accs = (double*)(ws + 10400000 + 5000802);  // 8B-aligned
  double* acc1 = accs;
  double* acc2 = accs + NB * 8;
  double* accF = accs + 2 * NB * 8;

  // --- build CSR permutation (same every call; dst is a static input) ---
  kz<<<GRIDE, BLK, 0, stream>>>(M_in, MA, hist, accs);
  khr<<<GRIDL, BLK, 0, stream>>>(dst, hist, rankpos);
  ksA<<<NBLKN, 256, 0, stream>>>(hist, bsum);
  ksB<<<1, 512, 0, stream>>>(bsum, bbase);
  ksC<<<NBLKN, 256, 0, stream>>>(hist, bbase, off);
  kp1<<<GRIDL, BLK, 0, stream>>>(dst, off, rankpos, eperm);
  kp2<<<GRIDL, BLK, 0, stream>>>(src, dst, H_in, eperm, sp, dp, Hp0);

  for (int l = 0; l < NLAYERS; ++l) {
    const float* Mc = (l & 1) ? MB : MA;
    float*       Mn = (l & 1) ? MA : MB;
    const float* Hc = (l & 1) ? Hp1 : Hp0;
    float*       Hw = (l & 1) ? Hp0 : Hp1;
    k1<<<GRID2, BLK, 0, stream>>>(Mc, Hc, sp, dp, we_w1, we_b1, acc1, acc2);
    k2<<<GRID2, BLK, 0, stream>>>(Mc, Hc, Hw, sp, dp, we_w1, we_b1, we_g1, we_be1,
                                  we_w2, we_b2, wv_w1, wv_b1, acc1, acc2,
                                  (l == NLAYERS - 1) ? 1 : 0, out_w1, out_b1, accF);
    if (l < NLAYERS - 1)
      k3<<<NBLKN, BLK, 0, stream>>>(
          Mc, Hw, off, wv_w1, wv_b1, wv_g1, wv_be1, wv_w2, wv_b2, acc2, acc1, Mn);
  }
  // final Hn lives in Hp0 (layer 19 wrote Hw = Hp0)
  f2<<<GRIDL, BLK, 0, stream>>>(Hp0, rankpos, out_w1, out_b1, out_g, out_be,
                                out_w2, out_b2, accF, (float*)d_out);
}

// Round 8
// 1276.873 us; speedup vs baseline: 1.2477x; 1.2477x over previous
//
#include <hip/hip_runtime.h>
#include <hip/hip_fp16.h>
#include <math.h>

#define NNODES 100000
#define NEDGES 1600000
#define NGROUP (NEDGES / 4)    // 4-edge groups
#define NLAYERS 20
#define NB 256          // accumulator banks == BLK
#define BLK 256
#define GRIDE 1024                          // stride kernels (setup)
#define STRIDE (GRIDE * BLK)
#define GRIDL ((NGROUP + BLK - 1) / BLK)    // 1563: one 4-edge group per thread
#define NBLKN ((NNODES + 255) / 256)        // 391 blocks for node kernels

struct __align__(8) H4 { __half h[4]; };    // 4 halfs, 8B load/store

// ---- block reduce of N float stats -> N parallel f64 atomics (one per lane) ----
template<int N>
__device__ __forceinline__ void block_stats_atomic(const float* vals, double* base) {
  __shared__ double sm[16][4];
  int lane = threadIdx.x & 63, wid = threadIdx.x >> 6;
  __syncthreads();                  // guard back-to-back calls reusing sm
  #pragma unroll
  for (int n = 0; n < N; ++n) {
    double d = (double)vals[n];
    #pragma unroll
    for (int o = 32; o > 0; o >>= 1) d += __shfl_down(d, o, 64);
    if (lane == 0) sm[n][wid] = d;
  }
  __syncthreads();
  if (threadIdx.x < N) {
    double s = sm[threadIdx.x][0] + sm[threadIdx.x][1] + sm[threadIdx.x][2] + sm[threadIdx.x][3];
    atomicAdd(base + threadIdx.x, s);
  }
}

// ---- cooperative reduction over NB banks: res[s] = sum_bk acc[bk*8+s] ----
template<int NS>
__device__ __forceinline__ void bank_reduce(const double* __restrict__ acc, double* res) {
  __shared__ double red[BLK * 8];   // 16 KB
  int t = threadIdx.x;
  #pragma unroll
  for (int s = 0; s < NS; ++s) red[t * 8 + s] = acc[t * 8 + s];
  __syncthreads();
  for (int o = BLK / 2; o > 0; o >>= 1) {
    if (t < o) {
      #pragma unroll
      for (int s = 0; s < NS; ++s) red[t * 8 + s] += red[(t + o) * 8 + s];
    }
    __syncthreads();
  }
  #pragma unroll
  for (int s = 0; s < NS; ++s) res[s] = red[s];
  __syncthreads();
}

// x = [mi, mj, h] @ W1 + b1  (9->4)
__device__ __forceinline__ void compute_x(const float4 mi, const float4 mj,
    float h0, float h1, float h2,
    const float* __restrict__ w, const float* __restrict__ b, float* x) {
  #pragma unroll
  for (int j = 0; j < 4; ++j) {
    float t = b[j];
    t += mi.x * w[0 * 4 + j]; t += mi.y * w[1 * 4 + j]; t += mi.z * w[2 * 4 + j];
    t += mj.x * w[3 * 4 + j]; t += mj.y * w[4 * 4 + j]; t += mj.z * w[5 * 4 + j];
    t += h0 * w[6 * 4 + j];  t += h1 * w[7 * 4 + j];  t += h2 * w[8 * 4 + j];
    x[j] = t;
  }
}

// ---------------- kz: pad-copy M, zero hist + accums ----------------
__global__ void __launch_bounds__(BLK) kz(const float* __restrict__ Min,
                                          float* __restrict__ M,
                                          int* __restrict__ hist,
                                          double* __restrict__ accs) {
  int tid = blockIdx.x * BLK + threadIdx.x;
  for (int v = tid; v < NNODES; v += STRIDE) {
    float4 m;
    m.x = Min[3 * v]; m.y = Min[3 * v + 1]; m.z = Min[3 * v + 2]; m.w = 0.f;
    *(float4*)(M + 4 * (size_t)v) = m;
    hist[v] = 0;
  }
  for (int i = tid; i < 3 * NB * 8; i += STRIDE) accs[i] = 0.0;
}

// ---------------- khr: histogram of dst, save rank (atomic return) ----------
__global__ void __launch_bounds__(BLK) khr(const int* __restrict__ dst,
                                           int* __restrict__ hist,
                                           int* __restrict__ rankpos) {
  int g = blockIdx.x * BLK + threadIdx.x;
  if (g >= NGROUP) return;
  int4 d4 = ((const int4*)dst)[g];
  int4 r;
  r.x = atomicAdd(&hist[d4.x], 1);
  r.y = atomicAdd(&hist[d4.y], 1);
  r.z = atomicAdd(&hist[d4.z], 1);
  r.w = atomicAdd(&hist[d4.w], 1);
  ((int4*)rankpos)[g] = r;
}

// ---------------- ksA: per-block sums of hist ----------------
__global__ void __launch_bounds__(256) ksA(const int* __restrict__ hist,
                                           int* __restrict__ bsum) {
  __shared__ int sm[256];
  int i = blockIdx.x * 256 + threadIdx.x;
  sm[threadIdx.x] = (i < NNODES) ? hist[i] : 0;
  __syncthreads();
  for (int o = 128; o > 0; o >>= 1) {
    if (threadIdx.x < o) sm[threadIdx.x] += sm[threadIdx.x + o];
    __syncthreads();
  }
  if (threadIdx.x == 0) bsum[blockIdx.x] = sm[0];
}

// ---------------- ksB: exclusive scan of the 391 block sums (1 block) -------
__global__ void __launch_bounds__(512) ksB(const int* __restrict__ bsum,
                                           int* __restrict__ bbase) {
  __shared__ int sm[512];
  int t = threadIdx.x;
  sm[t] = (t < NBLKN) ? bsum[t] : 0;
  __syncthreads();
  for (int o = 1; o < 512; o <<= 1) {
    int v = (t >= o) ? sm[t - o] : 0;
    __syncthreads();
    sm[t] += v;
    __syncthreads();
  }
  if (t < NBLKN) bbase[t] = (t == 0) ? 0 : sm[t - 1];
}

// ---------------- ksC: per-element offsets ----------------
__global__ void __launch_bounds__(256) ksC(const int* __restrict__ hist,
                                           const int* __restrict__ bbase,
                                           int* __restrict__ off) {
  __shared__ int sm[256];
  int t = threadIdx.x;
  int i = blockIdx.x * 256 + t;
  int v = (i < NNODES) ? hist[i] : 0;
  sm[t] = v;
  __syncthreads();
  for (int o = 1; o < 256; o <<= 1) {
    int u = (t >= o) ? sm[t - o] : 0;
    __syncthreads();
    sm[t] += u;
    __syncthreads();
  }
  if (i < NNODES) off[i] = bbase[blockIdx.x] + sm[t] - v;
  if (i == 0) off[NNODES] = NEDGES;
}

// ---------------- kp1: pos[e] = off[dst]+rank (in-place), eperm scatter -----
__global__ void __launch_bounds__(BLK) kp1(const int* __restrict__ dst,
                                           const int* __restrict__ off,
                                           int* __restrict__ rankpos,
                                           int* __restrict__ eperm) {
  int g = blockIdx.x * BLK + threadIdx.x;
  if (g >= NGROUP) return;
  int4 d4 = ((const int4*)dst)[g];
  int4 r4 = ((int4*)rankpos)[g];
  int4 p4;
  p4.x = off[d4.x] + r4.x;
  p4.y = off[d4.y] + r4.y;
  p4.z = off[d4.z] + r4.z;
  p4.w = off[d4.w] + r4.w;
  int e = 4 * g;
  eperm[p4.x] = e; eperm[p4.y] = e + 1; eperm[p4.z] = e + 2; eperm[p4.w] = e + 3;
  ((int4*)rankpos)[g] = p4;   // rankpos now holds pos[e]
}

// ---------------- kp2: gather into CSR order (H -> fp16), streaming writes ---
__global__ void __launch_bounds__(BLK) kp2(const int* __restrict__ src,
                                           const int* __restrict__ dst,
                                           const float* __restrict__ Hin,
                                           const int* __restrict__ eperm,
                                           int* __restrict__ sp,
                                           int* __restrict__ dp,
                                           __half* __restrict__ Hp) {
  int g = blockIdx.x * BLK + threadIdx.x;
  if (g >= NGROUP) return;
  int4 e4 = ((const int4*)eperm)[g];
  int4 s4, d4;
  s4.x = src[e4.x]; d4.x = dst[e4.x];
  s4.y = src[e4.y]; d4.y = dst[e4.y];
  s4.z = src[e4.z]; d4.z = dst[e4.z];
  s4.w = src[e4.w]; d4.w = dst[e4.w];
  __half hh[12];
  int ee[4] = {e4.x, e4.y, e4.z, e4.w};
  #pragma unroll
  for (int k = 0; k < 4; ++k) {
    size_t e3 = 3 * (size_t)ee[k];
    hh[3 * k]     = __float2half(Hin[e3]);
    hh[3 * k + 1] = __float2half(Hin[e3 + 1]);
    hh[3 * k + 2] = __float2half(Hin[e3 + 2]);
  }
  ((int4*)sp)[g] = s4;
  ((int4*)dp)[g] = d4;
  H4* Hv = (H4*)(Hp + 12 * (size_t)g);
  H4 a, b, c;
  #pragma unroll
  for (int i = 0; i < 4; ++i) { a.h[i] = hh[i]; b.h[i] = hh[4 + i]; c.h[i] = hh[8 + i]; }
  Hv[0] = a; Hv[1] = b; Hv[2] = c;
}

// ---------------- K1: stats of x = e_in @ W1 + b1 ; zero acc2 ----------------
__global__ void __launch_bounds__(BLK) k1(
    const float* __restrict__ M, const __half* __restrict__ H,
    const int* __restrict__ sp, const int* __restrict__ dp,
    const float* __restrict__ W1, const float* __restrict__ b1,
    double* __restrict__ acc1, double* __restrict__ acc2) {
  int g = blockIdx.x * BLK + threadIdx.x;
  if (blockIdx.x == 0)
    for (int i = threadIdx.x; i < NB * 8; i += BLK) acc2[i] = 0.0;

  float sx[4] = {0, 0, 0, 0}, sq[4] = {0, 0, 0, 0};
  if (g < NGROUP) {
    int4 s4 = ((const int4*)sp)[g];
    int4 d4 = ((const int4*)dp)[g];
    const H4* Hv = (const H4*)(H + 12 * (size_t)g);
    H4 a = Hv[0], b = Hv[1], c = Hv[2];
    float hf[12];
    #pragma unroll
    for (int i = 0; i < 4; ++i) {
      hf[i] = __half2float(a.h[i]); hf[4 + i] = __half2float(b.h[i]); hf[8 + i] = __half2float(c.h[i]);
    }
    float4 mi0 = *(const float4*)(M + 4 * (size_t)d4.x);
    float4 mj0 = *(const float4*)(M + 4 * (size_t)s4.x);
    float4 mi1 = *(const float4*)(M + 4 * (size_t)d4.y);
    float4 mj1 = *(const float4*)(M + 4 * (size_t)s4.y);
    float4 mi2 = *(const float4*)(M + 4 * (size_t)d4.z);
    float4 mj2 = *(const float4*)(M + 4 * (size_t)s4.z);
    float4 mi3 = *(const float4*)(M + 4 * (size_t)d4.w);
    float4 mj3 = *(const float4*)(M + 4 * (size_t)s4.w);
    float x[4][4];
    compute_x(mi0, mj0, hf[0], hf[1], hf[2],  W1, b1, x[0]);
    compute_x(mi1, mj1, hf[3], hf[4], hf[5],  W1, b1, x[1]);
    compute_x(mi2, mj2, hf[6], hf[7], hf[8],  W1, b1, x[2]);
    compute_x(mi3, mj3, hf[9], hf[10], hf[11], W1, b1, x[3]);
    #pragma unroll
    for (int k = 0; k < 4; ++k)
      #pragma unroll
      for (int j = 0; j < 4; ++j) { sx[j] += x[k][j]; sq[j] += x[k][j] * x[k][j]; }
  }
  float vals[8] = {sx[0], sx[1], sx[2], sx[3], sq[0], sq[1], sq[2], sq[3]};
  block_stats_atomic<8>(vals, acc1 + (size_t)(blockIdx.x & (NB - 1)) * 8);
}

// ---------------- K2: Hn per edge + stats of z ; (layer19) head-BN stats ----
__global__ void __launch_bounds__(BLK) k2(
    const float* __restrict__ M, const __half* __restrict__ H, __half* __restrict__ Hn,
    const int* __restrict__ sp, const int* __restrict__ dp,
    const float* __restrict__ W1, const float* __restrict__ b1,
    const float* __restrict__ g1, const float* __restrict__ be1,
    const float* __restrict__ W2, const float* __restrict__ b2,
    const float* __restrict__ V1, const float* __restrict__ vb1,
    const double* __restrict__ acc1, double* __restrict__ acc2,
    int isFinal,
    const float* __restrict__ OW1, const float* __restrict__ ob1,
    double* __restrict__ accF) {
  double red[8];
  bank_reduce<8>(acc1, red);
  float s1[4], t1[4];
  {
    const double invE = 1.0 / (double)NEDGES;
    #pragma unroll
    for (int j = 0; j < 4; ++j) {
      double m = red[j] * invE;
      double var = red[4 + j] * invE - m * m;
      double sc = (double)g1[j] / sqrt(var + 1e-5);
      s1[j] = (float)sc;
      t1[j] = (float)((double)be1[j] - m * sc);
    }
  }
  float sz[3] = {0, 0, 0}, szz[3] = {0, 0, 0}, sf[3] = {0, 0, 0}, sff[3] = {0, 0, 0};
  int g = blockIdx.x * BLK + threadIdx.x;
  if (g < NGROUP) {
    int4 s4 = ((const int4*)sp)[g];
    int4 d4 = ((const int4*)dp)[g];
    const H4* Hv = (const H4*)(H + 12 * (size_t)g);
    H4 ha = Hv[0], hb = Hv[1], hc = Hv[2];
    float hf[12];
    #pragma unroll
    for (int i = 0; i < 4; ++i) {
      hf[i] = __half2float(ha.h[i]); hf[4 + i] = __half2float(hb.h[i]); hf[8 + i] = __half2float(hc.h[i]);
    }
    float4 mi[4], mj[4];
    mi[0] = *(const float4*)(M + 4 * (size_t)d4.x);
    mj[0] = *(const float4*)(M + 4 * (size_t)s4.x);
    mi[1] = *(const float4*)(M + 4 * (size_t)d4.y);
    mj[1] = *(const float4*)(M + 4 * (size_t)s4.y);
    mi[2] = *(const float4*)(M + 4 * (size_t)d4.z);
    mj[2] = *(const float4*)(M + 4 * (size_t)s4.z);
    mi[3] = *(const float4*)(M + 4 * (size_t)d4.w);
    mj[3] = *(const float4*)(M + 4 * (size_t)s4.w);
    __half hh[12];
    float hnr[4][3];
    #pragma unroll
    for (int k = 0; k < 4; ++k) {
      float x[4], y[4];
      compute_x(mi[k], mj[k], hf[3 * k], hf[3 * k + 1], hf[3 * k + 2], W1, b1, x);
      #pragma unroll
      for (int j = 0; j < 4; ++j) y[j] = fmaxf(x[j] * s1[j] + t1[j], 0.f);
      #pragma unroll
      for (int c = 0; c < 3; ++c) {
        float v = b2[c] + y[0] * W2[0 * 3 + c] + y[1] * W2[1 * 3 + c]
                        + y[2] * W2[2 * 3 + c] + y[3] * W2[3 * 3 + c];
        __half hv = __float2half(v);
        hh[3 * k + c] = hv;
        hnr[k][c] = __half2float(hv);   // rounded value: what k1/k3 will read back
      }
      #pragma unroll
      for (int c = 0; c < 3; ++c) {
        float z = vb1[c] + mi[k].x * V1[0 * 3 + c] + mi[k].y * V1[1 * 3 + c] + mi[k].z * V1[2 * 3 + c]
                         + hnr[k][0] * V1[3 * 3 + c] + hnr[k][1] * V1[4 * 3 + c] + hnr[k][2] * V1[5 * 3 + c];
        sz[c] += z; szz[c] += z * z;
      }
      if (isFinal) {
        #pragma unroll
        for (int c = 0; c < 3; ++c) {
          float f = ob1[c] + hnr[k][0] * OW1[0 * 3 + c] + hnr[k][1] * OW1[1 * 3 + c] + hnr[k][2] * OW1[2 * 3 + c];
          sf[c] += f; sff[c] += f * f;
        }
      }
    }
    H4* Hw = (H4*)(Hn + 12 * (size_t)g);
    H4 oA, oB, oC;
    #pragma unroll
    for (int i = 0; i < 4; ++i) { oA.h[i] = hh[i]; oB.h[i] = hh[4 + i]; oC.h[i] = hh[8 + i]; }
    Hw[0] = oA; Hw[1] = oB; Hw[2] = oC;
  }
  size_t bank = (size_t)(blockIdx.x & (NB - 1)) * 8;
  float v6[6] = {sz[0], sz[1], sz[2], szz[0], szz[1], szz[2]};
  block_stats_atomic<6>(v6, acc2 + bank);
  if (isFinal) {
    float v6b[6] = {sf[0], sf[1], sf[2], sff[0], sff[1], sff[2]};
    block_stats_atomic<6>(v6b, accF + bank);
  }
}

// ---------------- K3: node-centric aggregation via CSR; zero acc1 ----------
__global__ void __launch_bounds__(BLK) k3(
    const float* __restrict__ M, const __half* __restrict__ Hn,
    const int* __restrict__ off,
    const float* __restrict__ V1, const float* __restrict__ vb1,
    const float* __restrict__ vg1, const float* __restrict__ vbe1,
    const float* __restrict__ V2, const float* __restrict__ vb2,
    const double* __restrict__ acc2, double* __restrict__ acc1,
    float* __restrict__ Mnew) {
  double red[6];
  bank_reduce<6>(acc2, red);
  float s2[3], t2[3];
  {
    const double invE = 1.0 / (double)NEDGES;
    #pragma unroll
    for (int c = 0; c < 3; ++c) {
      double m = red[c] * invE;
      double var = red[3 + c] * invE - m * m;
      double sc = (double)vg1[c] / sqrt(var + 1e-5);
      s2[c] = (float)sc;
      t2[c] = (float)((double)vbe1[c] - m * sc);
    }
  }
  if (blockIdx.x == 0)
    for (int i = threadIdx.x; i < NB * 8; i += BLK) acc1[i] = 0.0;

  int v = blockIdx.x * BLK + threadIdx.x;
  if (v >= NNODES) return;
  float4 mi = *(const float4*)(M + 4 * (size_t)v);
  int e0 = off[v], e1 = off[v + 1];
  float a0 = 0.f, a1 = 0.f, a2v = 0.f;
  for (int e = e0; e < e1; ++e) {
    size_t e3 = 3 * (size_t)e;
    float h0 = __half2float(Hn[e3]), h1 = __half2float(Hn[e3 + 1]), h2 = __half2float(Hn[e3 + 2]);
    float y[3];
    #pragma unroll
    for (int c = 0; c < 3; ++c) {
      float z = vb1[c] + mi.x * V1[0 * 3 + c] + mi.y * V1[1 * 3 + c] + mi.z * V1[2 * 3 + c]
                       + h0 * V1[3 * 3 + c] + h1 * V1[4 * 3 + c] + h2 * V1[5 * 3 + c];
      y[c] = fmaxf(z * s2[c] + t2[c], 0.f);
    }
    a0  += vb2[0] + y[0] * V2[0] + y[1] * V2[3] + y[2] * V2[6];
    a1  += vb2[1] + y[0] * V2[1] + y[1] * V2[4] + y[2] * V2[7];
    a2v += vb2[2] + y[0] * V2[2] + y[1] * V2[5] + y[2] * V2[8];
  }
  float4 o; o.x = a0; o.y = a1; o.z = a2v; o.w = 0.f;
  *(float4*)(Mnew + 4 * (size_t)v) = o;
}

// ---------------- head: gather H via pos, streamed out writes ----------------
__global__ void __launch_bounds__(BLK) f2(
    const __half* __restrict__ H, const int* __restrict__ pos,
    const float* __restrict__ OW1, const float* __restrict__ ob1,
    const float* __restrict__ og, const float* __restrict__ obe,
    const float* __restrict__ OW2, const float* __restrict__ ob2,
    const double* __restrict__ accF, float* __restrict__ out) {
  double red[6];
  bank_reduce<6>(accF, red);
  float sF[3], tF[3];
  {
    const double invE = 1.0 / (double)NEDGES;
    #pragma unroll
    for (int c = 0; c < 3; ++c) {
      double m = red[c] * invE;
      double var = red[3 + c] * invE - m * m;
      double sc = (double)og[c] / sqrt(var + 1e-5);
      sF[c] = (float)sc;
      tF[c] = (float)((double)obe[c] - m * sc);
    }
  }
  int g = blockIdx.x * BLK + threadIdx.x;
  if (g >= NGROUP) return;
  int4 p4 = ((const int4*)pos)[g];
  int p[4] = {p4.x, p4.y, p4.z, p4.w};
  float2 o[4];
  #pragma unroll
  for (int k = 0; k < 4; ++k) {
    size_t p3 = 3 * (size_t)p[k];
    float h0 = __half2float(H[p3]), h1 = __half2float(H[p3 + 1]), h2 = __half2float(H[p3 + 2]);
    float y[3];
    #pragma unroll
    for (int c = 0; c < 3; ++c) {
      float f = ob1[c] + h0 * OW1[0 * 3 + c] + h1 * OW1[1 * 3 + c] + h2 * OW1[2 * 3 + c];
      y[c] = fmaxf(f * sF[c] + tF[c], 0.f);
    }
    float l0 = ob2[0] + y[0] * OW2[0] + y[1] * OW2[2] + y[2] * OW2[4];
    float l1 = ob2[1] + y[0] * OW2[1] + y[1] * OW2[3] + y[2] * OW2[5];
    float mx = fmaxf(l0, l1);
    float e0 = __expf(l0 - mx), e1 = __expf(l1 - mx);
    float inv = 1.f / (e0 + e1);
    o[k].x = e0 * inv; o[k].y = e1 * inv;
  }
  float4 oA, oB;
  oA.x = o[0].x; oA.y = o[0].y; oA.z = o[1].x; oA.w = o[1].y;
  oB.x = o[2].x; oB.y = o[2].y; oB.z = o[3].x; oB.w = o[3].y;
  ((float4*)out)[2 * (size_t)g] = oA;
  ((float4*)out)[2 * (size_t)g + 1] = oB;
}

extern "C" void kernel_launch(void* const* d_in, const int* in_sizes, int n_in,
                              void* d_out, int out_size, void* d_ws, size_t ws_size,
                              hipStream_t stream) {
  const float* M_in   = (const float*)d_in[0];
  const float* H_in   = (const float*)d_in[1];
  const int*   ei     = (const int*)d_in[2];
  const float* we_w1  = (const float*)d_in[3];
  const float* we_b1  = (const float*)d_in[4];
  const float* we_g1  = (const float*)d_in[5];
  const float* we_be1 = (const float*)d_in[6];
  const float* we_w2  = (const float*)d_in[7];
  const float* we_b2  = (const float*)d_in[8];
  const float* wv_w1  = (const float*)d_in[9];
  const float* wv_b1  = (const float*)d_in[10];
  const float* wv_g1  = (const float*)d_in[11];
  const float* wv_be1 = (const float*)d_in[12];
  const float* wv_w2  = (const float*)d_in[13];
  const float* wv_b2  = (const float*)d_in[14];
  const float* out_w1 = (const float*)d_in[15];
  const float* out_b1 = (const float*)d_in[16];
  const float* out_g  = (const float*)d_in[17];
  const float* out_be = (const float*)d_in[18];
  const float* out_w2 = (const float*)d_in[19];
  const float* out_b2 = (const float*)d_in[20];
  const int* src = ei;
  const int* dst = ei + NEDGES;

  float* ws = (float*)d_ws;
  float* MA  = ws;                           // N*4 floats
  float* MB  = ws + 400000;                  // N*4 floats
  __half* Hp0 = (__half*)(ws + 800000);      // E*3 halfs (9.6 MB -> 2.4M float slots)
  __half* Hp1 = (__half*)(ws + 3200000);     // E*3 halfs
  int* eperm  = (int*)Hp1;                   // alias: dead before layer-0 k2 writes Hp1
  int* ib      = (int*)(ws + 5600000);       // byte 22.4M, 16B-aligned
  int* sp      = ib;                         // E
  int* dp      = ib + 1600000;               // E
  int* rankpos = ib + 3200000;               // E (rank, then pos)
  int* hist    = ib + 4800000;               // N
  int* off     = ib + 4900000;               // N+1
  int* bsum    = ib + 5000001;               // 400
  int* bbase   = ib + 5000401;               // 400
  double* accs = (double*)(ws + 5600000 + 5000802);  // even float idx -> 8B-aligned
  double* acc1 = accs;
  double* acc2 = accs + NB * 8;
  double* accF = accs + 2 * NB * 8;

  // --- build CSR permutation (same every call; dst is a static input) ---
  kz<<<GRIDE, BLK, 0, stream>>>(M_in, MA, hist, accs);
  khr<<<GRIDL, BLK, 0, stream>>>(dst, hist, rankpos);
  ksA<<<NBLKN, 256, 0, stream>>>(hist, bsum);
  ksB<<<1, 512, 0, stream>>>(bsum, bbase);
  ksC<<<NBLKN, 256, 0, stream>>>(hist, bbase, off);
  kp1<<<GRIDL, BLK, 0, stream>>>(dst, off, rankpos, eperm);
  kp2<<<GRIDL, BLK, 0, stream>>>(src, dst, H_in, eperm, sp, dp, Hp0);

  for (int l = 0; l < NLAYERS; ++l) {
    const float* Mc = (l & 1) ? MB : MA;
    float*       Mn = (l & 1) ? MA : MB;
    const __half* Hc = (l & 1) ? Hp1 : Hp0;
    __half*       Hw = (l & 1) ? Hp0 : Hp1;
    k1<<<GRIDL, BLK, 0, stream>>>(Mc, Hc, sp, dp, we_w1, we_b1, acc1, acc2);
    k2<<<GRIDL, BLK, 0, stream>>>(Mc, Hc, Hw, sp, dp, we_w1, we_b1, we_g1, we_be1,
                                  we_w2, we_b2, wv_w1, wv_b1, acc1, acc2,
                                  (l == NLAYERS - 1) ? 1 : 0, out_w1, out_b1, accF);
    if (l < NLAYERS - 1)
      k3<<<NBLKN, BLK, 0, stream>>>(
          Mc, Hw, off, wv_w1, wv_b1, wv_g1, wv_be1, wv_w2, wv_b2, acc2, acc1, Mn);
  }
  // final Hn lives in Hp0 (layer 19 wrote Hw = Hp0)
  f2<<<GRIDL, BLK, 0, stream>>>(Hp0, rankpos, out_w1, out_b1, out_g, out_be,
                                out_w2, out_b2, accF, (float*)d_out);
}

// Round 9
// 1223.748 us; speedup vs baseline: 1.3018x; 1.0434x over previous
//
#include <hip/hip_runtime.h>
#include <hip/hip_fp16.h>
#include <math.h>

#define NNODES 100000
#define NEDGES 1600000
#define NGROUP (NEDGES / 4)    // 4-edge groups
#define NLAYERS 20
#define NB 256          // accumulator banks == BLK
#define BLK 256
#define GRIDE 1024                          // stride kernels (setup)
#define STRIDE (GRIDE * BLK)
#define GRIDL ((NGROUP + BLK - 1) / BLK)    // 1563: one 4-edge group per thread
#define NBLKN ((NNODES + 255) / 256)        // 391 blocks for node kernels
#define GRIDN4 ((NNODES * 4 + BLK - 1) / BLK)  // 1563: 4 lanes per node (k3)

struct __align__(8) H4 { __half h[4]; };    // 4 halfs, 8B load/store

// ---- block reduce of N float stats -> N parallel f64 atomics (one per lane) ----
template<int N>
__device__ __forceinline__ void block_stats_atomic(const float* vals, double* base) {
  __shared__ double sm[16][4];
  int lane = threadIdx.x & 63, wid = threadIdx.x >> 6;
  __syncthreads();                  // guard back-to-back calls reusing sm
  #pragma unroll
  for (int n = 0; n < N; ++n) {
    double d = (double)vals[n];
    #pragma unroll
    for (int o = 32; o > 0; o >>= 1) d += __shfl_down(d, o, 64);
    if (lane == 0) sm[n][wid] = d;
  }
  __syncthreads();
  if (threadIdx.x < N) {
    double s = sm[threadIdx.x][0] + sm[threadIdx.x][1] + sm[threadIdx.x][2] + sm[threadIdx.x][3];
    atomicAdd(base + threadIdx.x, s);
  }
}

// ---- cooperative reduction over NB banks: res[s] = sum_bk acc[bk*8+s] ----
template<int NS>
__device__ __forceinline__ void bank_reduce(const double* __restrict__ acc, double* res) {
  __shared__ double red[BLK * 8];   // 16 KB
  int t = threadIdx.x;
  #pragma unroll
  for (int s = 0; s < NS; ++s) red[t * 8 + s] = acc[t * 8 + s];
  __syncthreads();
  for (int o = BLK / 2; o > 0; o >>= 1) {
    if (t < o) {
      #pragma unroll
      for (int s = 0; s < NS; ++s) red[t * 8 + s] += red[(t + o) * 8 + s];
    }
    __syncthreads();
  }
  #pragma unroll
  for (int s = 0; s < NS; ++s) res[s] = red[s];
  __syncthreads();
}

// x = [mi, mj, h] @ W1 + b1  (9->4)
__device__ __forceinline__ void compute_x(const float4 mi, const float4 mj,
    float h0, float h1, float h2,
    const float* __restrict__ w, const float* __restrict__ b, float* x) {
  #pragma unroll
  for (int j = 0; j < 4; ++j) {
    float t = b[j];
    t += mi.x * w[0 * 4 + j]; t += mi.y * w[1 * 4 + j]; t += mi.z * w[2 * 4 + j];
    t += mj.x * w[3 * 4 + j]; t += mj.y * w[4 * 4 + j]; t += mj.z * w[5 * 4 + j];
    t += h0 * w[6 * 4 + j];  t += h1 * w[7 * 4 + j];  t += h2 * w[8 * 4 + j];
    x[j] = t;
  }
}

// ---------------- kz: pad-copy M, zero hist + accums ----------------
__global__ void __launch_bounds__(BLK) kz(const float* __restrict__ Min,
                                          float* __restrict__ M,
                                          int* __restrict__ hist,
                                          double* __restrict__ accs) {
  int tid = blockIdx.x * BLK + threadIdx.x;
  for (int v = tid; v < NNODES; v += STRIDE) {
    float4 m;
    m.x = Min[3 * v]; m.y = Min[3 * v + 1]; m.z = Min[3 * v + 2]; m.w = 0.f;
    *(float4*)(M + 4 * (size_t)v) = m;
    hist[v] = 0;
  }
  for (int i = tid; i < 3 * NB * 8; i += STRIDE) accs[i] = 0.0;
}

// ---------------- khr: histogram of dst, save rank (atomic return) ----------
__global__ void __launch_bounds__(BLK) khr(const int* __restrict__ dst,
                                           int* __restrict__ hist,
                                           int* __restrict__ rankpos) {
  int g = blockIdx.x * BLK + threadIdx.x;
  if (g >= NGROUP) return;
  int4 d4 = ((const int4*)dst)[g];
  int4 r;
  r.x = atomicAdd(&hist[d4.x], 1);
  r.y = atomicAdd(&hist[d4.y], 1);
  r.z = atomicAdd(&hist[d4.z], 1);
  r.w = atomicAdd(&hist[d4.w], 1);
  ((int4*)rankpos)[g] = r;
}

// ---------------- ksA: per-block sums of hist ----------------
__global__ void __launch_bounds__(256) ksA(const int* __restrict__ hist,
                                           int* __restrict__ bsum) {
  __shared__ int sm[256];
  int i = blockIdx.x * 256 + threadIdx.x;
  sm[threadIdx.x] = (i < NNODES) ? hist[i] : 0;
  __syncthreads();
  for (int o = 128; o > 0; o >>= 1) {
    if (threadIdx.x < o) sm[threadIdx.x] += sm[threadIdx.x + o];
    __syncthreads();
  }
  if (threadIdx.x == 0) bsum[blockIdx.x] = sm[0];
}

// ---------------- ksB: exclusive scan of the 391 block sums (1 block) -------
__global__ void __launch_bounds__(512) ksB(const int* __restrict__ bsum,
                                           int* __restrict__ bbase) {
  __shared__ int sm[512];
  int t = threadIdx.x;
  sm[t] = (t < NBLKN) ? bsum[t] : 0;
  __syncthreads();
  for (int o = 1; o < 512; o <<= 1) {
    int v = (t >= o) ? sm[t - o] : 0;
    __syncthreads();
    sm[t] += v;
    __syncthreads();
  }
  if (t < NBLKN) bbase[t] = (t == 0) ? 0 : sm[t - 1];
}

// ---------------- ksC: per-element offsets ----------------
__global__ void __launch_bounds__(256) ksC(const int* __restrict__ hist,
                                           const int* __restrict__ bbase,
                                           int* __restrict__ off) {
  __shared__ int sm[256];
  int t = threadIdx.x;
  int i = blockIdx.x * 256 + t;
  int v = (i < NNODES) ? hist[i] : 0;
  sm[t] = v;
  __syncthreads();
  for (int o = 1; o < 256; o <<= 1) {
    int u = (t >= o) ? sm[t - o] : 0;
    __syncthreads();
    sm[t] += u;
    __syncthreads();
  }
  if (i < NNODES) off[i] = bbase[blockIdx.x] + sm[t] - v;
  if (i == 0) off[NNODES] = NEDGES;
}

// ---------------- kd: dp[p] = v for p in [off[v], off[v+1]) -----------------
__global__ void __launch_bounds__(BLK) kd(const int* __restrict__ off,
                                          int* __restrict__ dp) {
  int v = blockIdx.x * BLK + threadIdx.x;
  if (v >= NNODES) return;
  int e0 = off[v], e1 = off[v + 1];
  for (int e = e0; e < e1; ++e) dp[e] = v;
}

// ---------------- kp1: pos[e] = off[dst]+rank (in-place), eperm scatter -----
__global__ void __launch_bounds__(BLK) kp1(const int* __restrict__ dst,
                                           const int* __restrict__ off,
                                           int* __restrict__ rankpos,
                                           int* __restrict__ eperm) {
  int g = blockIdx.x * BLK + threadIdx.x;
  if (g >= NGROUP) return;
  int4 d4 = ((const int4*)dst)[g];
  int4 r4 = ((int4*)rankpos)[g];
  int4 p4;
  p4.x = off[d4.x] + r4.x;
  p4.y = off[d4.y] + r4.y;
  p4.z = off[d4.z] + r4.z;
  p4.w = off[d4.w] + r4.w;
  int e = 4 * g;
  eperm[p4.x] = e; eperm[p4.y] = e + 1; eperm[p4.z] = e + 2; eperm[p4.w] = e + 3;
  ((int4*)rankpos)[g] = p4;   // rankpos now holds pos[e]
}

// ---------------- kp2: gather src/H into CSR order (H -> fp16) --------------
__global__ void __launch_bounds__(BLK) kp2(const int* __restrict__ src,
                                           const float* __restrict__ Hin,
                                           const int* __restrict__ eperm,
                                           int* __restrict__ sp,
                                           __half* __restrict__ Hp) {
  int g = blockIdx.x * BLK + threadIdx.x;
  if (g >= NGROUP) return;
  int4 e4 = ((const int4*)eperm)[g];
  int4 s4;
  s4.x = src[e4.x];
  s4.y = src[e4.y];
  s4.z = src[e4.z];
  s4.w = src[e4.w];
  __half hh[12];
  int ee[4] = {e4.x, e4.y, e4.z, e4.w};
  #pragma unroll
  for (int k = 0; k < 4; ++k) {
    size_t e3 = 3 * (size_t)ee[k];
    hh[3 * k]     = __float2half(Hin[e3]);
    hh[3 * k + 1] = __float2half(Hin[e3 + 1]);
    hh[3 * k + 2] = __float2half(Hin[e3 + 2]);
  }
  ((int4*)sp)[g] = s4;
  H4* Hv = (H4*)(Hp + 12 * (size_t)g);
  H4 a, b, c;
  #pragma unroll
  for (int i = 0; i < 4; ++i) { a.h[i] = hh[i]; b.h[i] = hh[4 + i]; c.h[i] = hh[8 + i]; }
  Hv[0] = a; Hv[1] = b; Hv[2] = c;
}

// ---------------- K1: stats of x = e_in @ W1 + b1 ; zero acc2 ----------------
__global__ void __launch_bounds__(BLK) k1(
    const float* __restrict__ M, const __half* __restrict__ H,
    const int* __restrict__ sp, const int* __restrict__ dp,
    const float* __restrict__ W1, const float* __restrict__ b1,
    double* __restrict__ acc1, double* __restrict__ acc2) {
  int g = blockIdx.x * BLK + threadIdx.x;
  if (blockIdx.x == 0)
    for (int i = threadIdx.x; i < NB * 8; i += BLK) acc2[i] = 0.0;

  float sx[4] = {0, 0, 0, 0}, sq[4] = {0, 0, 0, 0};
  if (g < NGROUP) {
    int4 s4 = ((const int4*)sp)[g];
    int4 d4 = ((const int4*)dp)[g];
    const H4* Hv = (const H4*)(H + 12 * (size_t)g);
    H4 a = Hv[0], b = Hv[1], c = Hv[2];
    float hf[12];
    #pragma unroll
    for (int i = 0; i < 4; ++i) {
      hf[i] = __half2float(a.h[i]); hf[4 + i] = __half2float(b.h[i]); hf[8 + i] = __half2float(c.h[i]);
    }
    float4 mi0 = *(const float4*)(M + 4 * (size_t)d4.x);
    float4 mj0 = *(const float4*)(M + 4 * (size_t)s4.x);
    float4 mi1 = *(const float4*)(M + 4 * (size_t)d4.y);
    float4 mj1 = *(const float4*)(M + 4 * (size_t)s4.y);
    float4 mi2 = *(const float4*)(M + 4 * (size_t)d4.z);
    float4 mj2 = *(const float4*)(M + 4 * (size_t)s4.z);
    float4 mi3 = *(const float4*)(M + 4 * (size_t)d4.w);
    float4 mj3 = *(const float4*)(M + 4 * (size_t)s4.w);
    float x[4][4];
    compute_x(mi0, mj0, hf[0], hf[1], hf[2],  W1, b1, x[0]);
    compute_x(mi1, mj1, hf[3], hf[4], hf[5],  W1, b1, x[1]);
    compute_x(mi2, mj2, hf[6], hf[7], hf[8],  W1, b1, x[2]);
    compute_x(mi3, mj3, hf[9], hf[10], hf[11], W1, b1, x[3]);
    #pragma unroll
    for (int k = 0; k < 4; ++k)
      #pragma unroll
      for (int j = 0; j < 4; ++j) { sx[j] += x[k][j]; sq[j] += x[k][j] * x[k][j]; }
  }
  float vals[8] = {sx[0], sx[1], sx[2], sx[3], sq[0], sq[1], sq[2], sq[3]};
  block_stats_atomic<8>(vals, acc1 + (size_t)(blockIdx.x & (NB - 1)) * 8);
}

// ---------------- K2: Hn per edge + stats of z ; (layer19) head-BN stats ----
__global__ void __launch_bounds__(BLK) k2(
    const float* __restrict__ M, const __half* __restrict__ H, __half* __restrict__ Hn,
    const int* __restrict__ sp, const int* __restrict__ dp,
    const float* __restrict__ W1, const float* __restrict__ b1,
    const float* __restrict__ g1, const float* __restrict__ be1,
    const float* __restrict__ W2, const float* __restrict__ b2,
    const float* __restrict__ V1, const float* __restrict__ vb1,
    const double* __restrict__ acc1, double* __restrict__ acc2,
    int isFinal,
    const float* __restrict__ OW1, const float* __restrict__ ob1,
    double* __restrict__ accF) {
  double red[8];
  bank_reduce<8>(acc1, red);
  float s1[4], t1[4];
  {
    const double invE = 1.0 / (double)NEDGES;
    #pragma unroll
    for (int j = 0; j < 4; ++j) {
      double m = red[j] * invE;
      double var = red[4 + j] * invE - m * m;
      double sc = (double)g1[j] / sqrt(var + 1e-5);
      s1[j] = (float)sc;
      t1[j] = (float)((double)be1[j] - m * sc);
    }
  }
  float sz[3] = {0, 0, 0}, szz[3] = {0, 0, 0}, sf[3] = {0, 0, 0}, sff[3] = {0, 0, 0};
  int g = blockIdx.x * BLK + threadIdx.x;
  if (g < NGROUP) {
    int4 s4 = ((const int4*)sp)[g];
    int4 d4 = ((const int4*)dp)[g];
    const H4* Hv = (const H4*)(H + 12 * (size_t)g);
    H4 ha = Hv[0], hb = Hv[1], hc = Hv[2];
    float hf[12];
    #pragma unroll
    for (int i = 0; i < 4; ++i) {
      hf[i] = __half2float(ha.h[i]); hf[4 + i] = __half2float(hb.h[i]); hf[8 + i] = __half2float(hc.h[i]);
    }
    float4 mi[4], mj[4];
    mi[0] = *(const float4*)(M + 4 * (size_t)d4.x);
    mj[0] = *(const float4*)(M + 4 * (size_t)s4.x);
    mi[1] = *(const float4*)(M + 4 * (size_t)d4.y);
    mj[1] = *(const float4*)(M + 4 * (size_t)s4.y);
    mi[2] = *(const float4*)(M + 4 * (size_t)d4.z);
    mj[2] = *(const float4*)(M + 4 * (size_t)s4.z);
    mi[3] = *(const float4*)(M + 4 * (size_t)d4.w);
    mj[3] = *(const float4*)(M + 4 * (size_t)s4.w);
    __half hh[12];
    float hnr[4][3];
    #pragma unroll
    for (int k = 0; k < 4; ++k) {
      float x[4], y[4];
      compute_x(mi[k], mj[k], hf[3 * k], hf[3 * k + 1], hf[3 * k + 2], W1, b1, x);
      #pragma unroll
      for (int j = 0; j < 4; ++j) y[j] = fmaxf(x[j] * s1[j] + t1[j], 0.f);
      #pragma unroll
      for (int c = 0; c < 3; ++c) {
        float v = b2[c] + y[0] * W2[0 * 3 + c] + y[1] * W2[1 * 3 + c]
                        + y[2] * W2[2 * 3 + c] + y[3] * W2[3 * 3 + c];
        __half hv = __float2half(v);
        hh[3 * k + c] = hv;
        hnr[k][c] = __half2float(hv);   // rounded value: what k1/k3 will read back
      }
      #pragma unroll
      for (int c = 0; c < 3; ++c) {
        float z = vb1[c] + mi[k].x * V1[0 * 3 + c] + mi[k].y * V1[1 * 3 + c] + mi[k].z * V1[2 * 3 + c]
                         + hnr[k][0] * V1[3 * 3 + c] + hnr[k][1] * V1[4 * 3 + c] + hnr[k][2] * V1[5 * 3 + c];
        sz[c] += z; szz[c] += z * z;
      }
      if (isFinal) {
        #pragma unroll
        for (int c = 0; c < 3; ++c) {
          float f = ob1[c] + hnr[k][0] * OW1[0 * 3 + c] + hnr[k][1] * OW1[1 * 3 + c] + hnr[k][2] * OW1[2 * 3 + c];
          sf[c] += f; sff[c] += f * f;
        }
      }
    }
    H4* Hw = (H4*)(Hn + 12 * (size_t)g);
    H4 oA, oB, oC;
    #pragma unroll
    for (int i = 0; i < 4; ++i) { oA.h[i] = hh[i]; oB.h[i] = hh[4 + i]; oC.h[i] = hh[8 + i]; }
    Hw[0] = oA; Hw[1] = oB; Hw[2] = oC;
  }
  size_t bank = (size_t)(blockIdx.x & (NB - 1)) * 8;
  float v6[6] = {sz[0], sz[1], sz[2], szz[0], szz[1], szz[2]};
  block_stats_atomic<6>(v6, acc2 + bank);
  if (isFinal) {
    float v6b[6] = {sf[0], sf[1], sf[2], sff[0], sff[1], sff[2]};
    block_stats_atomic<6>(v6b, accF + bank);
  }
}

// ---------------- K3: node aggregation, 4 lanes per node; zero acc1 ---------
__global__ void __launch_bounds__(BLK) k3(
    const float* __restrict__ M, const __half* __restrict__ Hn,
    const int* __restrict__ off,
    const float* __restrict__ V1, const float* __restrict__ vb1,
    const float* __restrict__ vg1, const float* __restrict__ vbe1,
    const float* __restrict__ V2, const float* __restrict__ vb2,
    const double* __restrict__ acc2, double* __restrict__ acc1,
    float* __restrict__ Mnew) {
  double red[6];
  bank_reduce<6>(acc2, red);
  float s2[3], t2[3];
  {
    const double invE = 1.0 / (double)NEDGES;
    #pragma unroll
    for (int c = 0; c < 3; ++c) {
      double m = red[c] * invE;
      double var = red[3 + c] * invE - m * m;
      double sc = (double)vg1[c] / sqrt(var + 1e-5);
      s2[c] = (float)sc;
      t2[c] = (float)((double)vbe1[c] - m * sc);
    }
  }
  if (blockIdx.x == 0)
    for (int i = threadIdx.x; i < NB * 8; i += BLK) acc1[i] = 0.0;

  int idx = blockIdx.x * BLK + threadIdx.x;
  int v = idx >> 2, q = idx & 3;
  if (v >= NNODES) return;
  float4 mi = *(const float4*)(M + 4 * (size_t)v);
  int e0 = off[v], e1 = off[v + 1];
  float a0 = 0.f, a1 = 0.f, a2v = 0.f;
  for (int e = e0 + q; e < e1; e += 4) {
    size_t e3 = 3 * (size_t)e;
    float h0 = __half2float(Hn[e3]), h1 = __half2float(Hn[e3 + 1]), h2 = __half2float(Hn[e3 + 2]);
    float y[3];
    #pragma unroll
    for (int c = 0; c < 3; ++c) {
      float z = vb1[c] + mi.x * V1[0 * 3 + c] + mi.y * V1[1 * 3 + c] + mi.z * V1[2 * 3 + c]
                       + h0 * V1[3 * 3 + c] + h1 * V1[4 * 3 + c] + h2 * V1[5 * 3 + c];
      y[c] = fmaxf(z * s2[c] + t2[c], 0.f);
    }
    a0  += vb2[0] + y[0] * V2[0] + y[1] * V2[3] + y[2] * V2[6];
    a1  += vb2[1] + y[0] * V2[1] + y[1] * V2[4] + y[2] * V2[7];
    a2v += vb2[2] + y[0] * V2[2] + y[1] * V2[5] + y[2] * V2[8];
  }
  // reduce across the 4-lane cluster (lanes q=0..3 of this node)
  a0  += __shfl_down(a0, 2, 4);  a0  += __shfl_down(a0, 1, 4);
  a1  += __shfl_down(a1, 2, 4);  a1  += __shfl_down(a1, 1, 4);
  a2v += __shfl_down(a2v, 2, 4); a2v += __shfl_down(a2v, 1, 4);
  if (q == 0) {
    float4 o; o.x = a0; o.y = a1; o.z = a2v; o.w = 0.f;
    *(float4*)(Mnew + 4 * (size_t)v) = o;
  }
}

// ---------------- head: gather H via pos, streamed out writes ----------------
__global__ void __launch_bounds__(BLK) f2(
    const __half* __restrict__ H, const int* __restrict__ pos,
    const float* __restrict__ OW1, const float* __restrict__ ob1,
    const float* __restrict__ og, const float* __restrict__ obe,
    const float* __restrict__ OW2, const float* __restrict__ ob2,
    const double* __restrict__ accF, float* __restrict__ out) {
  double red[6];
  bank_reduce<6>(accF, red);
  float sF[3], tF[3];
  {
    const double invE = 1.0 / (double)NEDGES;
    #pragma unroll
    for (int c = 0; c < 3; ++c) {
      double m = red[c] * invE;
      double var = red[3 + c] * invE - m * m;
      double sc = (double)og[c] / sqrt(var + 1e-5);
      sF[c] = (float)sc;
      tF[c] = (float)((double)obe[c] - m * sc);
    }
  }
  int g = blockIdx.x * BLK + threadIdx.x;
  if (g >= NGROUP) return;
  int4 p4 = ((const int4*)pos)[g];
  int p[4] = {p4.x, p4.y, p4.z, p4.w};
  float2 o[4];
  #pragma unroll
  for (int k = 0; k < 4; ++k) {
    size_t p3 = 3 * (size_t)p[k];
    float h0 = __half2float(H[p3]), h1 = __half2float(H[p3 + 1]), h2 = __half2float(H[p3 + 2]);
    float y[3];
    #pragma unroll
    for (int c = 0; c < 3; ++c) {
      float f = ob1[c] + h0 * OW1[0 * 3 + c] + h1 * OW1[1 * 3 + c] + h2 * OW1[2 * 3 + c];
      y[c] = fmaxf(f * sF[c] + tF[c], 0.f);
    }
    float l0 = ob2[0] + y[0] * OW2[0] + y[1] * OW2[2] + y[2] * OW2[4];
    float l1 = ob2[1] + y[0] * OW2[1] + y[1] * OW2[3] + y[2] * OW2[5];
    float mx = fmaxf(l0, l1);
    float e0 = __expf(l0 - mx), e1 = __expf(l1 - mx);
    float inv = 1.f / (e0 + e1);
    o[k].x = e0 * inv; o[k].y = e1 * inv;
  }
  float4 oA, oB;
  oA.x = o[0].x; oA.y = o[0].y; oA.z = o[1].x; oA.w = o[1].y;
  oB.x = o[2].x; oB.y = o[2].y; oB.z = o[3].x; oB.w = o[3].y;
  ((float4*)out)[2 * (size_t)g] = oA;
  ((float4*)out)[2 * (size_t)g + 1] = oB;
}

extern "C" void kernel_launch(void* const* d_in, const int* in_sizes, int n_in,
                              void* d_out, int out_size, void* d_ws, size_t ws_size,
                              hipStream_t stream) {
  const float* M_in   = (const float*)d_in[0];
  const float* H_in   = (const float*)d_in[1];
  const int*   ei     = (const int*)d_in[2];
  const float* we_w1  = (const float*)d_in[3];
  const float* we_b1  = (const float*)d_in[4];
  const float* we_g1  = (const float*)d_in[5];
  const float* we_be1 = (const float*)d_in[6];
  const float* we_w2  = (const float*)d_in[7];
  const float* we_b2  = (const float*)d_in[8];
  const float* wv_w1  = (const float*)d_in[9];
  const float* wv_b1  = (const float*)d_in[10];
  const float* wv_g1  = (const float*)d_in[11];
  const float* wv_be1 = (const float*)d_in[12];
  const float* wv_w2  = (const float*)d_in[13];
  const float* wv_b2  = (const float*)d_in[14];
  const float* out_w1 = (const float*)d_in[15];
  const float* out_b1 = (const float*)d_in[16];
  const float* out_g  = (const float*)d_in[17];
  const float* out_be = (const float*)d_in[18];
  const float* out_w2 = (const float*)d_in[19];
  const float* out_b2 = (const float*)d_in[20];
  const int* src = ei;
  const int* dst = ei + NEDGES;

  float* ws = (float*)d_ws;
  float* MA  = ws;                           // N*4 floats
  float* MB  = ws + 400000;                  // N*4 floats
  __half* Hp0 = (__half*)(ws + 800000);      // E*3 halfs
  __half* Hp1 = (__half*)(ws + 3200000);     // E*3 halfs
  int* eperm  = (int*)Hp1;                   // alias: dead before layer-0 k2 writes Hp1
  int* ib      = (int*)(ws + 5600000);       // 16B-aligned
  int* sp      = ib;                         // E
  int* dp      = ib + 1600000;               // E
  int* rankpos = ib + 3200000;               // E (rank, then pos)
  int* hist    = ib + 4800000;               // N
  int* off     = ib + 4900000;               // N+1
  int* bsum    = ib + 5000001;               // 400
  int* bbase   = ib + 5000401;               // 400
  double* accs = (double*)(ws + 5600000 + 5000802);  // even float idx -> 8B-aligned
  double* acc1 = accs;
  double* acc2 = accs + NB * 8;
  double* accF = accs + 2 * NB * 8;

  // --- build CSR permutation (same every call; dst is a static input) ---
  kz<<<GRIDE, BLK, 0, stream>>>(M_in, MA, hist, accs);
  khr<<<GRIDL, BLK, 0, stream>>>(dst, hist, rankpos);
  ksA<<<NBLKN, 256, 0, stream>>>(hist, bsum);
  ksB<<<1, 512, 0, stream>>>(bsum, bbase);
  ksC<<<NBLKN, 256, 0, stream>>>(hist, bbase, off);
  kd<<<NBLKN, BLK, 0, stream>>>(off, dp);
  kp1<<<GRIDL, BLK, 0, stream>>>(dst, off, rankpos, eperm);
  kp2<<<GRIDL, BLK, 0, stream>>>(src, H_in, eperm, sp, Hp0);

  for (int l = 0; l < NLAYERS; ++l) {
    const float* Mc = (l & 1) ? MB : MA;
    float*       Mn = (l & 1) ? MA : MB;
    const __half* Hc = (l & 1) ? Hp1 : Hp0;
    __half*       Hw = (l & 1) ? Hp0 : Hp1;
    k1<<<GRIDL, BLK, 0, stream>>>(Mc, Hc, sp, dp, we_w1, we_b1, acc1, acc2);
    k2<<<GRIDL, BLK, 0, stream>>>(Mc, Hc, Hw, sp, dp, we_w1, we_b1, we_g1, we_be1,
                                  we_w2, we_b2, wv_w1, wv_b1, acc1, acc2,
                                  (l == NLAYERS - 1) ? 1 : 0, out_w1, out_b1, accF);
    if (l < NLAYERS - 1)
      k3<<<GRIDN4, BLK, 0, stream>>>(
          Mc, Hw, off, wv_w1, wv_b1, wv_g1, wv_be1, wv_w2, wv_b2, acc2, acc1, Mn);
  }
  // final Hn lives in Hp0 (layer 19 wrote Hw = Hp0)
  f2<<<GRIDL, BLK, 0, stream>>>(Hp0, rankpos, out_w1, out_b1, out_g, out_be,
                                out_w2, out_b2, accF, (float*)d_out);
}

// Round 10
// 1169.819 us; speedup vs baseline: 1.3619x; 1.0461x over previous
//
#include <hip/hip_runtime.h>
#include <hip/hip_fp16.h>
#include <math.h>

#define NNODES 100000
#define NEDGES 1600000
#define NGROUP (NEDGES / 4)    // 4-edge groups
#define NLAYERS 20
#define NB 256          // accumulator banks == BLK (keeps atomic chains ~6 deep)
#define BLK 256
#define GRIDE 1024                          // stride kernels (setup)
#define STRIDE (GRIDE * BLK)
#define GRIDL ((NGROUP + BLK - 1) / BLK)    // 1563: one 4-edge group per thread
#define NBLKN ((NNODES + 255) / 256)        // 391 blocks for node kernels
#define GRIDN4 ((NNODES * 4 + BLK - 1) / BLK)  // 4 lanes per node (k3)

struct __align__(8) H4 { __half h[4]; };    // 4 halfs, 8B load/store

// ---- block reduce of N float stats -> N parallel f64 atomics (one per lane) ----
template<int N>
__device__ __forceinline__ void block_stats_atomic(const float* vals, double* base) {
  __shared__ double sm[16][4];
  int lane = threadIdx.x & 63, wid = threadIdx.x >> 6;
  __syncthreads();                  // guard back-to-back calls reusing sm
  #pragma unroll
  for (int n = 0; n < N; ++n) {
    double d = (double)vals[n];
    #pragma unroll
    for (int o = 32; o > 0; o >>= 1) d += __shfl_down(d, o, 64);
    if (lane == 0) sm[n][wid] = d;
  }
  __syncthreads();
  if (threadIdx.x < N) {
    double s = sm[threadIdx.x][0] + sm[threadIdx.x][1] + sm[threadIdx.x][2] + sm[threadIdx.x][3];
    atomicAdd(base + threadIdx.x, s);
  }
}

// ---- prologue: reduce NB banks via per-wave shuffle butterfly (1 sync) ----
template<int NS>
__device__ __forceinline__ void bank_reduce(const double* __restrict__ acc, double* res) {
  __shared__ double part[4][8];
  int t = threadIdx.x;               // 256 threads = 4 waves x 64 = NB banks
  double v[NS];
  #pragma unroll
  for (int s = 0; s < NS; ++s) v[s] = acc[t * 8 + s];
  #pragma unroll
  for (int o = 32; o > 0; o >>= 1)
    #pragma unroll
    for (int s = 0; s < NS; ++s) v[s] += __shfl_down(v[s], o, 64);
  if ((t & 63) == 0) {
    int w = t >> 6;
    #pragma unroll
    for (int s = 0; s < NS; ++s) part[w][s] = v[s];
  }
  __syncthreads();
  #pragma unroll
  for (int s = 0; s < NS; ++s) res[s] = part[0][s] + part[1][s] + part[2][s] + part[3][s];
}

// x = [mi, mj, h] @ W1 + b1  (9->4)
__device__ __forceinline__ void compute_x(const float4 mi, const float4 mj,
    float h0, float h1, float h2,
    const float* __restrict__ w, const float* __restrict__ b, float* x) {
  #pragma unroll
  for (int j = 0; j < 4; ++j) {
    float t = b[j];
    t += mi.x * w[0 * 4 + j]; t += mi.y * w[1 * 4 + j]; t += mi.z * w[2 * 4 + j];
    t += mj.x * w[3 * 4 + j]; t += mj.y * w[4 * 4 + j]; t += mj.z * w[5 * 4 + j];
    t += h0 * w[6 * 4 + j];  t += h1 * w[7 * 4 + j];  t += h2 * w[8 * 4 + j];
    x[j] = t;
  }
}

// ---------------- kz: pad-copy M, zero hist + accums ----------------
__global__ void __launch_bounds__(BLK) kz(const float* __restrict__ Min,
                                          float* __restrict__ M,
                                          int* __restrict__ hist,
                                          double* __restrict__ accs) {
  int tid = blockIdx.x * BLK + threadIdx.x;
  for (int v = tid; v < NNODES; v += STRIDE) {
    float4 m;
    m.x = Min[3 * v]; m.y = Min[3 * v + 1]; m.z = Min[3 * v + 2]; m.w = 0.f;
    *(float4*)(M + 4 * (size_t)v) = m;
    hist[v] = 0;
  }
  for (int i = tid; i < 3 * NB * 8; i += STRIDE) accs[i] = 0.0;
}

// ---------------- khr: histogram of dst, save rank (atomic return) ----------
__global__ void __launch_bounds__(BLK) khr(const int* __restrict__ dst,
                                           int* __restrict__ hist,
                                           int* __restrict__ rankpos) {
  int g = blockIdx.x * BLK + threadIdx.x;
  if (g >= NGROUP) return;
  int4 d4 = ((const int4*)dst)[g];
  int4 r;
  r.x = atomicAdd(&hist[d4.x], 1);
  r.y = atomicAdd(&hist[d4.y], 1);
  r.z = atomicAdd(&hist[d4.z], 1);
  r.w = atomicAdd(&hist[d4.w], 1);
  ((int4*)rankpos)[g] = r;
}

// ---------------- ksA: per-block sums of hist ----------------
__global__ void __launch_bounds__(256) ksA(const int* __restrict__ hist,
                                           int* __restrict__ bsum) {
  __shared__ int sm[256];
  int i = blockIdx.x * 256 + threadIdx.x;
  sm[threadIdx.x] = (i < NNODES) ? hist[i] : 0;
  __syncthreads();
  for (int o = 128; o > 0; o >>= 1) {
    if (threadIdx.x < o) sm[threadIdx.x] += sm[threadIdx.x + o];
    __syncthreads();
  }
  if (threadIdx.x == 0) bsum[blockIdx.x] = sm[0];
}

// ---------------- ksB: exclusive scan of the 391 block sums (1 block) -------
__global__ void __launch_bounds__(512) ksB(const int* __restrict__ bsum,
                                           int* __restrict__ bbase) {
  __shared__ int sm[512];
  int t = threadIdx.x;
  sm[t] = (t < NBLKN) ? bsum[t] : 0;
  __syncthreads();
  for (int o = 1; o < 512; o <<= 1) {
    int v = (t >= o) ? sm[t - o] : 0;
    __syncthreads();
    sm[t] += v;
    __syncthreads();
  }
  if (t < NBLKN) bbase[t] = (t == 0) ? 0 : sm[t - 1];
}

// ---------------- ksC: per-element offsets + dp fill ----------------
__global__ void __launch_bounds__(256) ksC(const int* __restrict__ hist,
                                           const int* __restrict__ bbase,
                                           int* __restrict__ off,
                                           int* __restrict__ dp) {
  __shared__ int sm[256];
  int t = threadIdx.x;
  int i = blockIdx.x * 256 + t;
  int v = (i < NNODES) ? hist[i] : 0;
  sm[t] = v;
  __syncthreads();
  for (int o = 1; o < 256; o <<= 1) {
    int u = (t >= o) ? sm[t - o] : 0;
    __syncthreads();
    sm[t] += u;
    __syncthreads();
  }
  if (i < NNODES) {
    int ex = bbase[blockIdx.x] + sm[t] - v;
    off[i] = ex;
    for (int e = ex; e < ex + v; ++e) dp[e] = i;   // CSR-order dst fill
  }
  if (i == 0) off[NNODES] = NEDGES;
}

// ---------------- kpk: pack dp groups as {base, 3x u8 deltas} ----------------
__global__ void __launch_bounds__(BLK) kpk(const int* __restrict__ dp,
                                           int2* __restrict__ dpp) {
  int g = blockIdx.x * BLK + threadIdx.x;
  if (g >= NGROUP) return;
  int4 d4 = ((const int4*)dp)[g];
  int2 o;
  o.x = d4.x;
  o.y = (d4.y - d4.x) | ((d4.z - d4.x) << 8) | ((d4.w - d4.x) << 16);
  dpp[g] = o;
}

// ---------------- kp1: pos[e] = off[dst]+rank (in-place), eperm scatter -----
__global__ void __launch_bounds__(BLK) kp1(const int* __restrict__ dst,
                                           const int* __restrict__ off,
                                           int* __restrict__ rankpos,
                                           int* __restrict__ eperm) {
  int g = blockIdx.x * BLK + threadIdx.x;
  if (g >= NGROUP) return;
  int4 d4 = ((const int4*)dst)[g];
  int4 r4 = ((int4*)rankpos)[g];
  int4 p4;
  p4.x = off[d4.x] + r4.x;
  p4.y = off[d4.y] + r4.y;
  p4.z = off[d4.z] + r4.z;
  p4.w = off[d4.w] + r4.w;
  int e = 4 * g;
  eperm[p4.x] = e; eperm[p4.y] = e + 1; eperm[p4.z] = e + 2; eperm[p4.w] = e + 3;
  ((int4*)rankpos)[g] = p4;   // rankpos now holds pos[e]
}

// ---------------- kp2: gather src/H into CSR order (H -> fp16) --------------
__global__ void __launch_bounds__(BLK) kp2(const int* __restrict__ src,
                                           const float* __restrict__ Hin,
                                           const int* __restrict__ eperm,
                                           int* __restrict__ sp,
                                           __half* __restrict__ Hp) {
  int g = blockIdx.x * BLK + threadIdx.x;
  if (g >= NGROUP) return;
  int4 e4 = ((const int4*)eperm)[g];
  int4 s4;
  s4.x = src[e4.x];
  s4.y = src[e4.y];
  s4.z = src[e4.z];
  s4.w = src[e4.w];
  __half hh[12];
  int ee[4] = {e4.x, e4.y, e4.z, e4.w};
  #pragma unroll
  for (int k = 0; k < 4; ++k) {
    size_t e3 = 3 * (size_t)ee[k];
    hh[3 * k]     = __float2half(Hin[e3]);
    hh[3 * k + 1] = __float2half(Hin[e3 + 1]);
    hh[3 * k + 2] = __float2half(Hin[e3 + 2]);
  }
  ((int4*)sp)[g] = s4;
  H4* Hv = (H4*)(Hp + 12 * (size_t)g);
  H4 a, b, c;
  #pragma unroll
  for (int i = 0; i < 4; ++i) { a.h[i] = hh[i]; b.h[i] = hh[4 + i]; c.h[i] = hh[8 + i]; }
  Hv[0] = a; Hv[1] = b; Hv[2] = c;
}

// ---------------- K1: stats of x = e_in @ W1 + b1 ; zero acc2 ----------------
__global__ void __launch_bounds__(BLK) k1(
    const float* __restrict__ M, const __half* __restrict__ H,
    const int* __restrict__ sp, const int2* __restrict__ dpp,
    const float* __restrict__ W1, const float* __restrict__ b1,
    double* __restrict__ acc1, double* __restrict__ acc2) {
  int g = blockIdx.x * BLK + threadIdx.x;
  if (blockIdx.x == 0)
    for (int i = threadIdx.x; i < NB * 8; i += BLK) acc2[i] = 0.0;

  float sx[4] = {0, 0, 0, 0}, sq[4] = {0, 0, 0, 0};
  if (g < NGROUP) {
    int4 s4 = ((const int4*)sp)[g];
    int2 dppg = dpp[g];
    int d0 = dppg.x;
    int d1 = d0 + (dppg.y & 255);
    int d2 = d0 + ((dppg.y >> 8) & 255);
    int d3 = d0 + ((dppg.y >> 16) & 255);
    const H4* Hv = (const H4*)(H + 12 * (size_t)g);
    H4 a = Hv[0], b = Hv[1], c = Hv[2];
    float hf[12];
    #pragma unroll
    for (int i = 0; i < 4; ++i) {
      hf[i] = __half2float(a.h[i]); hf[4 + i] = __half2float(b.h[i]); hf[8 + i] = __half2float(c.h[i]);
    }
    float4 mi0 = *(const float4*)(M + 4 * (size_t)d0);
    float4 mj0 = *(const float4*)(M + 4 * (size_t)s4.x);
    float4 mi1 = *(const float4*)(M + 4 * (size_t)d1);
    float4 mj1 = *(const float4*)(M + 4 * (size_t)s4.y);
    float4 mi2 = *(const float4*)(M + 4 * (size_t)d2);
    float4 mj2 = *(const float4*)(M + 4 * (size_t)s4.z);
    float4 mi3 = *(const float4*)(M + 4 * (size_t)d3);
    float4 mj3 = *(const float4*)(M + 4 * (size_t)s4.w);
    float x[4][4];
    compute_x(mi0, mj0, hf[0], hf[1], hf[2],  W1, b1, x[0]);
    compute_x(mi1, mj1, hf[3], hf[4], hf[5],  W1, b1, x[1]);
    compute_x(mi2, mj2, hf[6], hf[7], hf[8],  W1, b1, x[2]);
    compute_x(mi3, mj3, hf[9], hf[10], hf[11], W1, b1, x[3]);
    #pragma unroll
    for (int k = 0; k < 4; ++k)
      #pragma unroll
      for (int j = 0; j < 4; ++j) { sx[j] += x[k][j]; sq[j] += x[k][j] * x[k][j]; }
  }
  float vals[8] = {sx[0], sx[1], sx[2], sx[3], sq[0], sq[1], sq[2], sq[3]};
  block_stats_atomic<8>(vals, acc1 + (size_t)(blockIdx.x & (NB - 1)) * 8);
}

// ---------------- K2: Hn per edge + stats of z ; (layer19) head-BN stats ----
__global__ void __launch_bounds__(BLK) k2(
    const float* __restrict__ M, const __half* __restrict__ H, __half* __restrict__ Hn,
    const int* __restrict__ sp, const int2* __restrict__ dpp,
    const float* __restrict__ W1, const float* __restrict__ b1,
    const float* __restrict__ g1, const float* __restrict__ be1,
    const float* __restrict__ W2, const float* __restrict__ b2,
    const float* __restrict__ V1, const float* __restrict__ vb1,
    const double* __restrict__ acc1, double* __restrict__ acc2,
    int isFinal,
    const float* __restrict__ OW1, const float* __restrict__ ob1,
    double* __restrict__ accF) {
  double red[8];
  bank_reduce<8>(acc1, red);
  float s1[4], t1[4];
  {
    const double invE = 1.0 / (double)NEDGES;
    #pragma unroll
    for (int j = 0; j < 4; ++j) {
      double m = red[j] * invE;
      double var = red[4 + j] * invE - m * m;
      double sc = (double)g1[j] / sqrt(var + 1e-5);
      s1[j] = (float)sc;
      t1[j] = (float)((double)be1[j] - m * sc);
    }
  }
  float sz[3] = {0, 0, 0}, szz[3] = {0, 0, 0}, sf[3] = {0, 0, 0}, sff[3] = {0, 0, 0};
  int g = blockIdx.x * BLK + threadIdx.x;
  if (g < NGROUP) {
    int4 s4 = ((const int4*)sp)[g];
    int2 dppg = dpp[g];
    int dd[4];
    dd[0] = dppg.x;
    dd[1] = dd[0] + (dppg.y & 255);
    dd[2] = dd[0] + ((dppg.y >> 8) & 255);
    dd[3] = dd[0] + ((dppg.y >> 16) & 255);
    const H4* Hv = (const H4*)(H + 12 * (size_t)g);
    H4 ha = Hv[0], hb = Hv[1], hc = Hv[2];
    float hf[12];
    #pragma unroll
    for (int i = 0; i < 4; ++i) {
      hf[i] = __half2float(ha.h[i]); hf[4 + i] = __half2float(hb.h[i]); hf[8 + i] = __half2float(hc.h[i]);
    }
    float4 mi[4], mj[4];
    mi[0] = *(const float4*)(M + 4 * (size_t)dd[0]);
    mj[0] = *(const float4*)(M + 4 * (size_t)s4.x);
    mi[1] = *(const float4*)(M + 4 * (size_t)dd[1]);
    mj[1] = *(const float4*)(M + 4 * (size_t)s4.y);
    mi[2] = *(const float4*)(M + 4 * (size_t)dd[2]);
    mj[2] = *(const float4*)(M + 4 * (size_t)s4.z);
    mi[3] = *(const float4*)(M + 4 * (size_t)dd[3]);
    mj[3] = *(const float4*)(M + 4 * (size_t)s4.w);
    __half hh[12];
    float hnr[4][3];
    #pragma unroll
    for (int k = 0; k < 4; ++k) {
      float x[4], y[4];
      compute_x(mi[k], mj[k], hf[3 * k], hf[3 * k + 1], hf[3 * k + 2], W1, b1, x);
      #pragma unroll
      for (int j = 0; j < 4; ++j) y[j] = fmaxf(x[j] * s1[j] + t1[j], 0.f);
      #pragma unroll
      for (int c = 0; c < 3; ++c) {
        float v = b2[c] + y[0] * W2[0 * 3 + c] + y[1] * W2[1 * 3 + c]
                        + y[2] * W2[2 * 3 + c] + y[3] * W2[3 * 3 + c];
        __half hv = __float2half(v);
        hh[3 * k + c] = hv;
        hnr[k][c] = __half2float(hv);   // rounded value: what k1/k3 will read back
      }
      #pragma unroll
      for (int c = 0; c < 3; ++c) {
        float z = vb1[c] + mi[k].x * V1[0 * 3 + c] + mi[k].y * V1[1 * 3 + c] + mi[k].z * V1[2 * 3 + c]
                         + hnr[k][0] * V1[3 * 3 + c] + hnr[k][1] * V1[4 * 3 + c] + hnr[k][2] * V1[5 * 3 + c];
        sz[c] += z; szz[c] += z * z;
      }
      if (isFinal) {
        #pragma unroll
        for (int c = 0; c < 3; ++c) {
          float f = ob1[c] + hnr[k][0] * OW1[0 * 3 + c] + hnr[k][1] * OW1[1 * 3 + c] + hnr[k][2] * OW1[2 * 3 + c];
          sf[c] += f; sff[c] += f * f;
        }
      }
    }
    H4* Hw = (H4*)(Hn + 12 * (size_t)g);
    H4 oA, oB, oC;
    #pragma unroll
    for (int i = 0; i < 4; ++i) { oA.h[i] = hh[i]; oB.h[i] = hh[4 + i]; oC.h[i] = hh[8 + i]; }
    Hw[0] = oA; Hw[1] = oB; Hw[2] = oC;
  }
  size_t bank = (size_t)(blockIdx.x & (NB - 1)) * 8;
  float v6[6] = {sz[0], sz[1], sz[2], szz[0], szz[1], szz[2]};
  block_stats_atomic<6>(v6, acc2 + bank);
  if (isFinal) {
    float v6b[6] = {sf[0], sf[1], sf[2], sff[0], sff[1], sff[2]};
    block_stats_atomic<6>(v6b, accF + bank);
  }
}

// ---------------- K3: node aggregation, 4 lanes per node; zero acc1 ---------
__global__ void __launch_bounds__(BLK) k3(
    const float* __restrict__ M, const __half* __restrict__ Hn,
    const int* __restrict__ off,
    const float* __restrict__ V1, const float* __restrict__ vb1,
    const float* __restrict__ vg1, const float* __restrict__ vbe1,
    const float* __restrict__ V2, const float* __restrict__ vb2,
    const double* __restrict__ acc2, double* __restrict__ acc1,
    float* __restrict__ Mnew) {
  double red[6];
  bank_reduce<6>(acc2, red);
  float s2[3], t2[3];
  {
    const double invE = 1.0 / (double)NEDGES;
    #pragma unroll
    for (int c = 0; c < 3; ++c) {
      double m = red[c] * invE;
      double var = red[3 + c] * invE - m * m;
      double sc = (double)vg1[c] / sqrt(var + 1e-5);
      s2[c] = (float)sc;
      t2[c] = (float)((double)vbe1[c] - m * sc);
    }
  }
  if (blockIdx.x == 0)
    for (int i = threadIdx.x; i < NB * 8; i += BLK) acc1[i] = 0.0;

  int idx = blockIdx.x * BLK + threadIdx.x;
  int v = idx >> 2, q = idx & 3;
  if (v >= NNODES) return;
  float4 mi = *(const float4*)(M + 4 * (size_t)v);
  int e0 = off[v], e1 = off[v + 1];
  float a0 = 0.f, a1 = 0.f, a2v = 0.f;
  for (int e = e0 + q; e < e1; e += 4) {
    size_t e3 = 3 * (size_t)e;
    float h0 = __half2float(Hn[e3]), h1 = __half2float(Hn[e3 + 1]), h2 = __half2float(Hn[e3 + 2]);
    float y[3];
    #pragma unroll
    for (int c = 0; c < 3; ++c) {
      float z = vb1[c] + mi.x * V1[0 * 3 + c] + mi.y * V1[1 * 3 + c] + mi.z * V1[2 * 3 + c]
                       + h0 * V1[3 * 3 + c] + h1 * V1[4 * 3 + c] + h2 * V1[5 * 3 + c];
      y[c] = fmaxf(z * s2[c] + t2[c], 0.f);
    }
    a0  += vb2[0] + y[0] * V2[0] + y[1] * V2[3] + y[2] * V2[6];
    a1  += vb2[1] + y[0] * V2[1] + y[1] * V2[4] + y[2] * V2[7];
    a2v += vb2[2] + y[0] * V2[2] + y[1] * V2[5] + y[2] * V2[8];
  }
  a0  += __shfl_down(a0, 2, 4);  a0  += __shfl_down(a0, 1, 4);
  a1  += __shfl_down(a1, 2, 4);  a1  += __shfl_down(a1, 1, 4);
  a2v += __shfl_down(a2v, 2, 4); a2v += __shfl_down(a2v, 1, 4);
  if (q == 0) {
    float4 o; o.x = a0; o.y = a1; o.z = a2v; o.w = 0.f;
    *(float4*)(Mnew + 4 * (size_t)v) = o;
  }
}

// ---------------- head: gather H via pos, streamed out writes ----------------
__global__ void __launch_bounds__(BLK) f2(
    const __half* __restrict__ H, const int* __restrict__ pos,
    const float* __restrict__ OW1, const float* __restrict__ ob1,
    const float* __restrict__ og, const float* __restrict__ obe,
    const float* __restrict__ OW2, const float* __restrict__ ob2,
    const double* __restrict__ accF, float* __restrict__ out) {
  double red[6];
  bank_reduce<6>(accF, red);
  float sF[3], tF[3];
  {
    const double invE = 1.0 / (double)NEDGES;
    #pragma unroll
    for (int c = 0; c < 3; ++c) {
      double m = red[c] * invE;
      double var = red[3 + c] * invE - m * m;
      double sc = (double)og[c] / sqrt(var + 1e-5);
      sF[c] = (float)sc;
      tF[c] = (float)((double)obe[c] - m * sc);
    }
  }
  int g = blockIdx.x * BLK + threadIdx.x;
  if (g >= NGROUP) return;
  int4 p4 = ((const int4*)pos)[g];
  int p[4] = {p4.x, p4.y, p4.z, p4.w};
  float2 o[4];
  #pragma unroll
  for (int k = 0; k < 4; ++k) {
    size_t p3 = 3 * (size_t)p[k];
    float h0 = __half2float(H[p3]), h1 = __half2float(H[p3 + 1]), h2 = __half2float(H[p3 + 2]);
    float y[3];
    #pragma unroll
    for (int c = 0; c < 3; ++c) {
      float f = ob1[c] + h0 * OW1[0 * 3 + c] + h1 * OW1[1 * 3 + c] + h2 * OW1[2 * 3 + c];
      y[c] = fmaxf(f * sF[c] + tF[c], 0.f);
    }
    float l0 = ob2[0] + y[0] * OW2[0] + y[1] * OW2[2] + y[2] * OW2[4];
    float l1 = ob2[1] + y[0] * OW2[1] + y[1] * OW2[3] + y[2] * OW2[5];
    float mx = fmaxf(l0, l1);
    float e0 = __expf(l0 - mx), e1 = __expf(l1 - mx);
    float inv = 1.f / (e0 + e1);
    o[k].x = e0 * inv; o[k].y = e1 * inv;
  }
  float4 oA, oB;
  oA.x = o[0].x; oA.y = o[0].y; oA.z = o[1].x; oA.w = o[1].y;
  oB.x = o[2].x; oB.y = o[2].y; oB.z = o[3].x; oB.w = o[3].y;
  ((float4*)out)[2 * (size_t)g] = oA;
  ((float4*)out)[2 * (size_t)g + 1] = oB;
}

extern "C" void kernel_launch(void* const* d_in, const int* in_sizes, int n_in,
                              void* d_out, int out_size, void* d_ws, size_t ws_size,
                              hipStream_t stream) {
  const float* M_in   = (const float*)d_in[0];
  const float* H_in   = (const float*)d_in[1];
  const int*   ei     = (const int*)d_in[2];
  const float* we_w1  = (const float*)d_in[3];
  const float* we_b1  = (const float*)d_in[4];
  const float* we_g1  = (const float*)d_in[5];
  const float* we_be1 = (const float*)d_in[6];
  const float* we_w2  = (const float*)d_in[7];
  const float* we_b2  = (const float*)d_in[8];
  const float* wv_w1  = (const float*)d_in[9];
  const float* wv_b1  = (const float*)d_in[10];
  const float* wv_g1  = (const float*)d_in[11];
  const float* wv_be1 = (const float*)d_in[12];
  const float* wv_w2  = (const float*)d_in[13];
  const float* wv_b2  = (const float*)d_in[14];
  const float* out_w1 = (const float*)d_in[15];
  const float* out_b1 = (const float*)d_in[16];
  const float* out_g  = (const float*)d_in[17];
  const float* out_be = (const float*)d_in[18];
  const float* out_w2 = (const float*)d_in[19];
  const float* out_b2 = (const float*)d_in[20];
  const int* src = ei;
  const int* dst = ei + NEDGES;

  float* ws = (float*)d_ws;
  float* MA  = ws;                           // N*4 floats
  float* MB  = ws + 400000;                  // N*4 floats
  __half* Hp0 = (__half*)(ws + 800000);      // E*3 halfs
  __half* Hp1 = (__half*)(ws + 3200000);     // E*3 halfs
  int* eperm  = (int*)Hp1;                   // alias: dead before layer-0 k2 writes Hp1
  int* ib      = (int*)(ws + 5600000);       // 16B-aligned
  int* sp      = ib;                         // E
  int* dp      = ib + 1600000;               // E (CSR dst, setup only)
  int* rankpos = ib + 3200000;               // E (rank, then pos)
  int2* dpp    = (int2*)(ib + 4800000);      // E/4 int2 = E/2 ints
  int* hist    = ib + 5600000;               // N
  int* off     = ib + 5700000;               // N+1
  int* bsum    = ib + 5800001;               // 400
  int* bbase   = ib + 5800401;               // 400
  double* accs = (double*)(ws + 5600000 + 5800802);  // even float idx -> 8B-aligned
  double* acc1 = accs;
  double* acc2 = accs + NB * 8;
  double* accF = accs + 2 * NB * 8;

  // --- build CSR permutation (same every call; dst is a static input) ---
  kz<<<GRIDE, BLK, 0, stream>>>(M_in, MA, hist, accs);
  khr<<<GRIDL, BLK, 0, stream>>>(dst, hist, rankpos);
  ksA<<<NBLKN, 256, 0, stream>>>(hist, bsum);
  ksB<<<1, 512, 0, stream>>>(bsum, bbase);
  ksC<<<NBLKN, 256, 0, stream>>>(hist, bbase, off, dp);
  kpk<<<GRIDL, BLK, 0, stream>>>(dp, dpp);
  kp1<<<GRIDL, BLK, 0, stream>>>(dst, off, rankpos, eperm);
  kp2<<<GRIDL, BLK, 0, stream>>>(src, H_in, eperm, sp, Hp0);

  for (int l = 0; l < NLAYERS; ++l) {
    const float* Mc = (l & 1) ? MB : MA;
    float*       Mn = (l & 1) ? MA : MB;
    const __half* Hc = (l & 1) ? Hp1 : Hp0;
    __half*       Hw = (l & 1) ? Hp0 : Hp1;
    k1<<<GRIDL, BLK, 0, stream>>>(Mc, Hc, sp, dpp, we_w1, we_b1, acc1, acc2);
    k2<<<GRIDL, BLK, 0, stream>>>(Mc, Hc, Hw, sp, dpp, we_w1, we_b1, we_g1, we_be1,
                                  we_w2, we_b2, wv_w1, wv_b1, acc1, acc2,
                                  (l == NLAYERS - 1) ? 1 : 0, out_w1, out_b1, accF);
    if (l < NLAYERS - 1)
      k3<<<GRIDN4, BLK, 0, stream>>>(
          Mc, Hw, off, wv_w1, wv_b1, wv_g1, wv_be1, wv_w2, wv_b2, acc2, acc1, Mn);
  }
  // final Hn lives in Hp0 (layer 19 wrote Hw = Hp0)
  f2<<<GRIDL, BLK, 0, stream>>>(Hp0, rankpos, out_w1, out_b1, out_g, out_be,
                                out_w2, out_b2, accF, (float*)d_out);
}